// Round 3
// baseline (2562.654 us; speedup 1.0000x reference)
//
#include <hip/hip_runtime.h>

#define T_LEN 131072
#define RD 32
#define SD 512
#define QD 256
#define NL 27
#define KTOT (NL * RD)   // 864
#define GRID_F 512       // persistent-layer grid; 2 blocks/CU (capacity 4)
#define CHUNK 256        // t-span per persistent block (= max dilation)

typedef __attribute__((ext_vector_type(8))) short short8;
typedef __attribute__((ext_vector_type(4))) float floatx4;

__device__ __forceinline__ unsigned short f2bf(float f) {
    union { float f; unsigned int i; } v; v.f = f;
    unsigned int r = v.i + 0x7fffu + ((v.i >> 16) & 1u);  // RNE
    return (unsigned short)(r >> 16);
}

__device__ __forceinline__ void gload_lds16(const void* g, void* l) {
    __builtin_amdgcn_global_load_lds(
        (const __attribute__((address_space(1))) unsigned int*)g,
        (__attribute__((address_space(3))) unsigned int*)l, 16, 0, 0);
}

// ---------------- initial conv: [1,T] -> [T][32] fp32; also zero sync flags ----------------
__global__ __launch_bounds__(256)
void k_conv_init(const float* __restrict__ x, const float* __restrict__ Wc,
                 const float* __restrict__ bc, float* __restrict__ xout,
                 int* __restrict__ flags)
{
    // zero the producer-consumer flags for this iteration (graph replays!)
    if (threadIdx.x < NL) flags[(size_t)threadIdx.x * GRID_F + blockIdx.x] = 0;

    const int t = blockIdx.x * 256 + threadIdx.x;
    const float xm = (t > 0) ? x[t - 1] : 0.f;
    const float x0 = x[t];
    const float xp = (t < T_LEN - 1) ? x[t + 1] : 0.f;
    float* row = xout + (size_t)t * RD;
#pragma unroll
    for (int o = 0; o < RD; ++o) {
        row[o] = bc[o] + Wc[o * 3 + 0] * xm + Wc[o * 3 + 1] * x0 + Wc[o * 3 + 2] * xp;
    }
}

// ---------------- weight prep ----------------
__global__ __launch_bounds__(256)
void k_wprep(const float* __restrict__ Wt, const float* __restrict__ Ws,
             const float* __restrict__ Wd,
             unsigned short* __restrict__ Wg, unsigned short* __restrict__ Wdb)
{
    const int idx = blockIdx.x * 256 + threadIdx.x;
    const int n1 = NL * 64 * 96;
    const int n2 = NL * RD * RD;
    if (idx < n1) {
        const int l = idx / (64 * 96);
        const int rem = idx % (64 * 96);
        const int m = rem / 96;
        const int k = rem % 96;
        const int j = k / 32;
        const int c = k % 32;
        float v;
        if (m < 32) v = Wt[(((size_t)l * RD + m) * RD + c) * 3 + j];
        else        v = Ws[(((size_t)l * RD + (m - 32)) * RD + c) * 3 + j];
        Wg[idx] = f2bf(v);
    } else if (idx < n1 + n2) {
        const int i2 = idx - n1;
        Wdb[i2] = f2bf(Wd[i2]);
    }
}

// ---------------- ALL 27 residual layers in ONE persistent kernel ----------------
// 512 persistent blocks, each owns a 256-wide t-chunk. Dilation <= 256 ==
// CHUNK, so layer l+1 needs only the immediate neighbors' layer-l output.
// Producer: write xout -> __syncthreads (drains stores to L2) -> tid0:
// __threadfence (agent release: L2 writeback) + agent-scope flag store.
// Consumer: tid0 spins on flags[l-1][b-1], [b+1] -> __threadfence (acquire:
// invalidate stale L1/L2) -> __syncthreads. Own-chunk data needs no flag.
// Layer 26's xout is dead (reference overwrites x with skip path): phase B
// and its flag are skipped.
__global__ __launch_bounds__(256, 2)   // min 2 waves/EU => VGPR<=256 => >=2 blocks/CU resident
void k_layers_fused(const float* __restrict__ x0,
                    float* __restrict__ xa, float* __restrict__ xb,
                    unsigned short* __restrict__ Gt,      // [NL][T][32]
                    const unsigned short* __restrict__ WgAll,   // [NL][64][96]
                    const unsigned short* __restrict__ WdbAll,  // [NL][32][32]
                    const float* __restrict__ btAll,
                    const float* __restrict__ bsAll,
                    const float* __restrict__ bdAll,
                    int* __restrict__ flags)              // [NL][GRID_F]
{
    static const int dil[NL] = {1, 2, 4, 8, 16, 32, 64, 128, 256,
                                1, 2, 4, 8, 16, 32, 64, 128, 256,
                                1, 2, 4, 8, 16, 32, 64, 128, 256};
    __shared__ unsigned short gtile[128 * 32];  // 8 KB
    const int b = blockIdx.x;
    const int tid = threadIdx.x;
    const int lane = tid & 63;
    const int w = tid >> 6;
    const int quad = lane >> 4;
    const int l16 = lane & 15;
    const floatx4 vzero = {0.f, 0.f, 0.f, 0.f};

    for (int l = 0; l < NL; ++l) {
        const int d = dil[l];
        const float* xin = (l == 0) ? x0 : ((l & 1) ? xa : xb);
        float* xout = (l & 1) ? xb : xa;
        const unsigned short* Wg = WgAll + (size_t)l * 64 * 96;
        const unsigned short* Wdb = WdbAll + (size_t)l * RD * RD;
        const float* bt = btAll + (size_t)l * RD;
        const float* bs = bsAll + (size_t)l * RD;
        const float* bd = bdAll + (size_t)l * RD;

        // ---- wait for neighbors' previous layer ----
        if (l > 0) {
            if (tid == 0) {
                if (b > 0)
                    while (__hip_atomic_load(&flags[(size_t)(l - 1) * GRID_F + b - 1],
                                             __ATOMIC_RELAXED, __HIP_MEMORY_SCOPE_AGENT) == 0)
                        __builtin_amdgcn_s_sleep(1);
                if (b < GRID_F - 1)
                    while (__hip_atomic_load(&flags[(size_t)(l - 1) * GRID_F + b + 1],
                                             __ATOMIC_RELAXED, __HIP_MEMORY_SCOPE_AGENT) == 0)
                        __builtin_amdgcn_s_sleep(1);
                __threadfence();   // acquire: invalidate stale cached halo lines
            }
            __syncthreads();
        }

        // ---- per-layer weight fragments ----
        short8 afr[3][4];
#pragma unroll
        for (int j = 0; j < 3; ++j)
#pragma unroll
            for (int mt = 0; mt < 4; ++mt)
                afr[j][mt] = *reinterpret_cast<const short8*>(
                    Wg + (size_t)(mt * 16 + l16) * 96 + j * 32 + quad * 8);

        short8 ad[2];
#pragma unroll
        for (int mt = 0; mt < 2; ++mt)
            ad[mt] = *reinterpret_cast<const short8*>(Wdb + (size_t)(mt * 16 + l16) * 32 + quad * 8);

        // ---- two 128-wide sub-tiles per chunk ----
        for (int st = 0; st < 2; ++st) {
            const int tbase = b * CHUNK + st * 128 + w * 32;

            floatx4 acc[4][2];
#pragma unroll
            for (int mt = 0; mt < 4; ++mt)
#pragma unroll
                for (int nt = 0; nt < 2; ++nt) acc[mt][nt] = vzero;

#pragma unroll
            for (int nt = 0; nt < 2; ++nt) {
                const int t = tbase + nt * 16 + l16;
#pragma unroll
                for (int j = 0; j < 3; ++j) {
                    const int tt = t + (j - 1) * d;
                    short8 bb;
                    if (tt >= 0 && tt < T_LEN) {
                        const float* src = xin + (size_t)tt * RD + quad * 8;
                        const floatx4 f0 = *reinterpret_cast<const floatx4*>(src);
                        const floatx4 f1 = *reinterpret_cast<const floatx4*>(src + 4);
#pragma unroll
                        for (int i = 0; i < 4; ++i) {
                            bb[i] = (short)f2bf(f0[i]);
                            bb[4 + i] = (short)f2bf(f1[i]);
                        }
                    } else {
#pragma unroll
                        for (int i = 0; i < 8; ++i) bb[i] = 0;
                    }
#pragma unroll
                    for (int mt = 0; mt < 4; ++mt)
                        acc[mt][nt] = __builtin_amdgcn_mfma_f32_16x16x32_bf16(afr[j][mt], bb, acc[mt][nt], 0, 0, 0);
                }
            }

#pragma unroll
            for (int nt = 0; nt < 2; ++nt) {
                const int t = tbase + nt * 16 + l16;
                const int tloc = w * 32 + nt * 16 + l16;
#pragma unroll
                for (int pair = 0; pair < 2; ++pair) {
                    const floatx4 bt4 = *reinterpret_cast<const floatx4*>(bt + pair * 16 + quad * 4);
                    const floatx4 bs4 = *reinterpret_cast<const floatx4*>(bs + pair * 16 + quad * 4);
                    ushort4 u;
                    unsigned short us[4];
#pragma unroll
                    for (int r = 0; r < 4; ++r) {
                        const float a1 = acc[pair][nt][r] + bt4[r];
                        const float a2 = acc[2 + pair][nt][r] + bs4[r];
                        const float th = 1.f - __fdividef(2.f, __expf(2.f * a1) + 1.f);
                        const float sg = __fdividef(1.f, 1.f + __expf(-a2));
                        us[r] = f2bf(th * sg);
                    }
                    u.x = us[0]; u.y = us[1]; u.z = us[2]; u.w = us[3];
                    const int cbase = pair * 16 + quad * 4;
                    *reinterpret_cast<ushort4*>(&gtile[tloc * 32 + cbase]) = u;
                    *reinterpret_cast<ushort4*>(
                        Gt + ((size_t)l * T_LEN + t) * RD + cbase) = u;
                }
            }

            __syncthreads();

            if (l < NL - 1) {   // layer 26's residual output is dead code
#pragma unroll
                for (int nt = 0; nt < 2; ++nt) {
                    const int t = tbase + nt * 16 + l16;
                    const int tloc = w * 32 + nt * 16 + l16;
                    const short8 bg = *reinterpret_cast<const short8*>(&gtile[tloc * 32 + quad * 8]);
#pragma unroll
                    for (int mt = 0; mt < 2; ++mt) {
                        const floatx4 a2 = __builtin_amdgcn_mfma_f32_16x16x32_bf16(ad[mt], bg, vzero, 0, 0, 0);
                        const int m = mt * 16 + quad * 4;
                        const floatx4 bd4 = *reinterpret_cast<const floatx4*>(bd + m);
                        const floatx4 xi = *reinterpret_cast<const floatx4*>(xin + (size_t)t * RD + m);
                        floatx4 o;
                        o[0] = a2[0] + bd4[0] + xi[0];
                        o[1] = a2[1] + bd4[1] + xi[1];
                        o[2] = a2[2] + bd4[2] + xi[2];
                        o[3] = a2[3] + bd4[3] + xi[3];
                        *reinterpret_cast<floatx4*>(xout + (size_t)t * RD + m) = o;
                    }
                }
            }
            __syncthreads();   // gtile reusable; all waves' stores drained
        }

        // ---- publish this layer's chunk ----
        if (l < NL - 1 && tid == 0) {
            __threadfence();   // release: write back dirty L2 so neighbors see xout
            __hip_atomic_store(&flags[(size_t)l * GRID_F + b], 1,
                               __ATOMIC_RELEASE, __HIP_MEMORY_SCOPE_AGENT);
        }
    }
}

// ---------------- Wcomb (chunk-major [27][512][32]) ----------------
__global__ __launch_bounds__(256)
void k_wcomb(const float* __restrict__ Wp1, const float* __restrict__ Wskip,
             unsigned short* __restrict__ Wcomb)
{
    const int idx = blockIdx.x * 256 + threadIdx.x;
    if (idx >= SD * KTOT) return;
    const int m = idx / KTOT;
    const int k = idx % KTOT;
    const int l = k / RD;
    const int c = k % RD;
    const float* wp1r = Wp1 + (size_t)m * SD;
    const float* wsk = Wskip + (size_t)l * SD * RD + c;
    float acc = 0.f;
    for (int j = 0; j < SD; ++j) acc += wp1r[j] * wsk[(size_t)j * RD];
    Wcomb[((size_t)l * SD + m) * RD + c] = f2bf(acc);
}

// ---------------- hbias ----------------
__global__ __launch_bounds__(512)
void k_hbias(const float* __restrict__ Wp1, const float* __restrict__ bp1,
             const float* __restrict__ bskip, float* __restrict__ hbias)
{
    __shared__ float sb[SD];
    const int tid = threadIdx.x;
    float s = 0.f;
    for (int l = 0; l < NL; ++l) s += bskip[l * SD + tid];
    sb[tid] = s;
    __syncthreads();
    float acc = bp1[tid];
    const float* r = Wp1 + (size_t)tid * SD;
    for (int j = 0; j < SD; ++j) acc += r[j] * sb[j];
    hbias[tid] = acc;
}

// ---------------- fp32 -> bf16 cast ----------------
__global__ __launch_bounds__(256)
void k_cvt(const float* __restrict__ src, unsigned short* __restrict__ dst, int n)
{
    const int i = blockIdx.x * 256 + threadIdx.x;
    if (i < n) dst[i] = f2bf(src[i]);
}

// ---------------- GEMM1: ht = relu(hbias + Wcomb@Gt) ----------------
__global__ __launch_bounds__(256)
void k_gemm1(const unsigned short* __restrict__ A,   // Wcomb [27][512][32]
             const unsigned short* __restrict__ B,   // Gt [27][T][32]
             const float* __restrict__ hbias,
             unsigned short* __restrict__ ht)        // [16][T][32]
{
    __shared__ unsigned short ldsA[128 * 32];  // 8 KB
    __shared__ unsigned short ldsB[128 * 32];  // 8 KB
    const int tid = threadIdx.x;
    const int lane = tid & 63;
    const int w = tid >> 6;
    const int wm = w & 1;
    const int wn = w >> 1;
    const int quad = lane >> 4;
    const int l16 = lane & 15;

    const int g = blockIdx.x;
    const int m0 = ((g >> 3) & 3) * 128;
    const int n0 = ((g & 7) + 8 * (g >> 5)) * 128;

    const int r4 = lane >> 2;
    const int c4 = lane & 3;
    const int srcc = c4 ^ ((r4 >> 1) & 3);   // permuted global chunk
    const int swz = (l16 >> 1) & 3;          // reader-side key

    floatx4 acc[4][4];
    const floatx4 vzero = {0.f, 0.f, 0.f, 0.f};
#pragma unroll
    for (int mt = 0; mt < 4; ++mt)
#pragma unroll
        for (int nt = 0; nt < 4; ++nt) acc[mt][nt] = vzero;

    const unsigned short* pA = A + (size_t)(m0 + r4) * RD + srcc * 8;
    const unsigned short* pB = B + (size_t)(n0 + r4) * RD + srcc * 8;

    for (int kc = 0; kc < KTOT / 32; ++kc) {
#pragma unroll
        for (int c = 0; c < 2; ++c) {
            const int row = w * 32 + c * 16;
            gload_lds16(pA + ((size_t)kc * SD + row) * RD, &ldsA[(size_t)row * 32]);
            gload_lds16(pB + ((size_t)kc * T_LEN + row) * RD, &ldsB[(size_t)row * 32]);
        }
        __syncthreads();

        short8 afr[4], bfr[4];
#pragma unroll
        for (int mt = 0; mt < 4; ++mt)
            afr[mt] = *reinterpret_cast<const short8*>(
                &ldsA[(wm * 64 + mt * 16 + l16) * 32 + (quad ^ swz) * 8]);
#pragma unroll
        for (int nt = 0; nt < 4; ++nt)
            bfr[nt] = *reinterpret_cast<const short8*>(
                &ldsB[(wn * 64 + nt * 16 + l16) * 32 + (quad ^ swz) * 8]);
#pragma unroll
        for (int mt = 0; mt < 4; ++mt)
#pragma unroll
            for (int nt = 0; nt < 4; ++nt)
                acc[mt][nt] = __builtin_amdgcn_mfma_f32_16x16x32_bf16(afr[mt], bfr[nt], acc[mt][nt], 0, 0, 0);
        __syncthreads();
    }

#pragma unroll
    for (int mt = 0; mt < 4; ++mt) {
        const int m = m0 + wm * 64 + mt * 16 + quad * 4;
        const floatx4 hb = *reinterpret_cast<const floatx4*>(hbias + m);
        const size_t chunkbase = (size_t)(m >> 5) * T_LEN;
        const int mc = m & 31;
#pragma unroll
        for (int nt = 0; nt < 4; ++nt) {
            const int t = n0 + wn * 64 + nt * 16 + l16;
            ushort4 st;
            float v;
            v = acc[mt][nt][0] + hb[0]; st.x = f2bf(v > 0.f ? v : 0.f);
            v = acc[mt][nt][1] + hb[1]; st.y = f2bf(v > 0.f ? v : 0.f);
            v = acc[mt][nt][2] + hb[2]; st.z = f2bf(v > 0.f ? v : 0.f);
            v = acc[mt][nt][3] + hb[3]; st.w = f2bf(v > 0.f ? v : 0.f);
            *reinterpret_cast<ushort4*>(ht + (chunkbase + t) * RD + mc) = st;
        }
    }
}

// ---------------- GEMM2 + fused log_softmax, LDS-staged B ----------------
__global__ __launch_bounds__(256)
void k_gemm2_lsm(const unsigned short* __restrict__ A,  // Wp2b [256][512] bf16
                 const unsigned short* __restrict__ B,  // ht [16][T][32] bf16
                 const float* __restrict__ bp2,
                 float* __restrict__ out)               // [256][T] fp32
{
    __shared__ unsigned short ldsB[64 * 32];  // 4 KB
    __shared__ float redmax[4 * 16 * 16];
    __shared__ float redsum[4 * 16 * 16];
    const int tid = threadIdx.x;
    const int lane = tid & 63;
    const int w = tid >> 6;   // 0..3 = m-slice
    const int quad = lane >> 4;
    const int l16 = lane & 15;
    const int m0 = w * 64;
    const int n0 = blockIdx.x * 64;

    const int r4 = lane >> 2;
    const int c4 = lane & 3;
    const int srcc = c4 ^ ((r4 >> 1) & 3);
    const int swz = (l16 >> 1) & 3;

    const unsigned short* ab[4];
#pragma unroll
    for (int mt = 0; mt < 4; ++mt)
        ab[mt] = A + (size_t)(m0 + mt * 16 + l16) * SD + quad * 8;

    const unsigned short* pB = B + (size_t)(n0 + w * 16 + r4) * RD + srcc * 8;

    floatx4 acc[4][4];
    const floatx4 vzero = {0.f, 0.f, 0.f, 0.f};
#pragma unroll
    for (int mt = 0; mt < 4; ++mt)
#pragma unroll
        for (int nt = 0; nt < 4; ++nt) acc[mt][nt] = vzero;

    for (int kc = 0; kc < SD / 32; ++kc) {
        const int k0 = kc * 32;
        gload_lds16(pB + (size_t)kc * T_LEN * RD, &ldsB[(size_t)(w * 16) * 32]);
        short8 afr[4];
#pragma unroll
        for (int mt = 0; mt < 4; ++mt)
            afr[mt] = *reinterpret_cast<const short8*>(ab[mt] + k0);
        __syncthreads();

        short8 bfr[4];
#pragma unroll
        for (int nt = 0; nt < 4; ++nt)
            bfr[nt] = *reinterpret_cast<const short8*>(
                &ldsB[(nt * 16 + l16) * 32 + (quad ^ swz) * 8]);
#pragma unroll
        for (int mt = 0; mt < 4; ++mt)
#pragma unroll
            for (int nt = 0; nt < 4; ++nt)
                acc[mt][nt] = __builtin_amdgcn_mfma_f32_16x16x32_bf16(
                    afr[mt], bfr[nt], acc[mt][nt], 0, 0, 0);
        __syncthreads();
    }

#pragma unroll
    for (int mt = 0; mt < 4; ++mt) {
        const int mb = m0 + mt * 16 + quad * 4;
        const floatx4 bz = *reinterpret_cast<const floatx4*>(bp2 + mb);
#pragma unroll
        for (int nt = 0; nt < 4; ++nt)
#pragma unroll
            for (int j = 0; j < 4; ++j) acc[mt][nt][j] += bz[j];
    }

#pragma unroll
    for (int nt = 0; nt < 4; ++nt) {
        float lm = -1e30f;
#pragma unroll
        for (int mt = 0; mt < 4; ++mt)
#pragma unroll
            for (int j = 0; j < 4; ++j) lm = fmaxf(lm, acc[mt][nt][j]);
        redmax[nt * 256 + l16 * 16 + w * 4 + quad] = lm;
    }
    __syncthreads();

    float lse[4];
#pragma unroll
    for (int nt = 0; nt < 4; ++nt) {
        float gm = -1e30f;
#pragma unroll
        for (int i = 0; i < 16; ++i) gm = fmaxf(gm, redmax[nt * 256 + l16 * 16 + i]);
        float ls = 0.f;
#pragma unroll
        for (int mt = 0; mt < 4; ++mt)
#pragma unroll
            for (int j = 0; j < 4; ++j) ls += __expf(acc[mt][nt][j] - gm);
        redsum[nt * 256 + l16 * 16 + w * 4 + quad] = ls;
        lse[nt] = gm;
    }
    __syncthreads();

#pragma unroll
    for (int nt = 0; nt < 4; ++nt) {
        float tot = 0.f;
#pragma unroll
        for (int i = 0; i < 16; ++i) tot += redsum[nt * 256 + l16 * 16 + i];
        lse[nt] = lse[nt] + __logf(tot);
    }

#pragma unroll
    for (int mt = 0; mt < 4; ++mt) {
        const int mb = m0 + mt * 16 + quad * 4;
#pragma unroll
        for (int nt = 0; nt < 4; ++nt) {
            const int t = n0 + nt * 16 + l16;
#pragma unroll
            for (int j = 0; j < 4; ++j)
                out[(size_t)(mb + j) * T_LEN + t] = acc[mt][nt][j] - lse[nt];
        }
    }
}

extern "C" void kernel_launch(void* const* d_in, const int* in_sizes, int n_in,
                              void* d_out, int out_size, void* d_ws, size_t ws_size,
                              hipStream_t stream)
{
    (void)in_sizes; (void)n_in; (void)out_size; (void)ws_size;
    const float* x     = (const float*)d_in[0];
    const float* Wc    = (const float*)d_in[1];
    const float* bc    = (const float*)d_in[2];
    const float* Wt    = (const float*)d_in[3];
    const float* bt    = (const float*)d_in[4];
    const float* Ws    = (const float*)d_in[5];
    const float* bs    = (const float*)d_in[6];
    const float* Wskip = (const float*)d_in[7];
    const float* bskip = (const float*)d_in[8];
    const float* Wd    = (const float*)d_in[9];
    const float* bd    = (const float*)d_in[10];
    const float* Wp1   = (const float*)d_in[11];
    const float* bp1   = (const float*)d_in[12];
    const float* Wp2   = (const float*)d_in[13];
    const float* bp2   = (const float*)d_in[14];
    float* out = (float*)d_out;

    char* p = (char*)d_ws;
    unsigned short* Gt = (unsigned short*)p;    p += (size_t)T_LEN * KTOT * 2;   // 226.5 MB, [27][T][32]
    unsigned short* ht = (unsigned short*)p;    p += (size_t)T_LEN * SD * 2;     // 134 MB, [16][T][32]
    unsigned short* Wcomb = (unsigned short*)p; p += (size_t)SD * KTOT * 2;
    unsigned short* Wp2b = (unsigned short*)p;  p += (size_t)QD * SD * 2;
    unsigned short* Wg = (unsigned short*)p;    p += (size_t)NL * 64 * 96 * 2;
    unsigned short* Wdb = (unsigned short*)p;   p += (size_t)NL * RD * RD * 2;
    float* hbias = (float*)p;                   p += (size_t)SD * 4;
    int* flags = (int*)p;                       p += (size_t)NL * GRID_F * 4;

    // x buffers alias the ht region (dead before gemm1 writes ht):
    // x0 (conv output) + ping-pong xa/xb = 48 MB < 134 MB
    char* q = (char*)ht;
    float* x0 = (float*)q;                      q += (size_t)T_LEN * RD * 4;
    float* xa = (float*)q;                      q += (size_t)T_LEN * RD * 4;
    float* xb = (float*)q;                      q += (size_t)T_LEN * RD * 4;

    k_wcomb<<<(SD * KTOT + 255) / 256, 256, 0, stream>>>(Wp1, Wskip, Wcomb);
    k_hbias<<<1, 512, 0, stream>>>(Wp1, bp1, bskip, hbias);
    k_cvt<<<(QD * SD + 255) / 256, 256, 0, stream>>>(Wp2, Wp2b, QD * SD);
    {
        const int nprep = NL * 64 * 96 + NL * RD * RD;
        k_wprep<<<(nprep + 255) / 256, 256, 0, stream>>>(Wt, Ws, Wd, Wg, Wdb);
    }
    k_conv_init<<<T_LEN / 256, 256, 0, stream>>>(x, Wc, bc, x0, flags);

    k_layers_fused<<<GRID_F, 256, 0, stream>>>(
        x0, xa, xb, Gt, Wg, Wdb, bt, bs, bd, flags);

    k_gemm1<<<4 * (T_LEN / 128), 256, 0, stream>>>(Wcomb, Gt, hbias, ht);
    k_gemm2_lsm<<<T_LEN / 64, 256, 0, stream>>>(Wp2b, ht, bp2, out);
}

// Round 4
// 1044.728 us; speedup vs baseline: 2.4529x; 2.4529x over previous
//
#include <hip/hip_runtime.h>

#define T_LEN 131072
#define RD 32
#define SD 512
#define QD 256
#define NL 27
#define KTOT (NL * RD)   // 864

// group-fusion geometry: 7 layers (d=1..64), halo = 128 >= 1+2+...+64 = 127
#define GC 256           // owned rows per block
#define GH 128           // halo rows per side
#define GR 512           // staged rows = GC + 2*GH
#define GNL 7

typedef __attribute__((ext_vector_type(8))) short short8;
typedef __attribute__((ext_vector_type(4))) float floatx4;

__device__ __forceinline__ unsigned short f2bf(float f) {
    union { float f; unsigned int i; } v; v.f = f;
    unsigned int r = v.i + 0x7fffu + ((v.i >> 16) & 1u);  // RNE
    return (unsigned short)(r >> 16);
}

__device__ __forceinline__ void gload_lds16(const void* g, void* l) {
    __builtin_amdgcn_global_load_lds(
        (const __attribute__((address_space(1))) unsigned int*)g,
        (__attribute__((address_space(3))) unsigned int*)l, 16, 0, 0);
}

// ---------------- initial conv: [1,T] -> [T][32] fp32 ----------------
__global__ __launch_bounds__(256)
void k_conv_init(const float* __restrict__ x, const float* __restrict__ Wc,
                 const float* __restrict__ bc, float* __restrict__ xout)
{
    const int t = blockIdx.x * 256 + threadIdx.x;
    const float xm = (t > 0) ? x[t - 1] : 0.f;
    const float x0 = x[t];
    const float xp = (t < T_LEN - 1) ? x[t + 1] : 0.f;
    float* row = xout + (size_t)t * RD;
#pragma unroll
    for (int o = 0; o < RD; ++o) {
        row[o] = bc[o] + Wc[o * 3 + 0] * xm + Wc[o * 3 + 1] * x0 + Wc[o * 3 + 2] * xp;
    }
}

// ---------------- weight prep ----------------
__global__ __launch_bounds__(256)
void k_wprep(const float* __restrict__ Wt, const float* __restrict__ Ws,
             const float* __restrict__ Wd,
             unsigned short* __restrict__ Wg, unsigned short* __restrict__ Wdb)
{
    const int idx = blockIdx.x * 256 + threadIdx.x;
    const int n1 = NL * 64 * 96;
    const int n2 = NL * RD * RD;
    if (idx < n1) {
        const int l = idx / (64 * 96);
        const int rem = idx % (64 * 96);
        const int m = rem / 96;
        const int k = rem % 96;
        const int j = k / 32;
        const int c = k % 32;
        float v;
        if (m < 32) v = Wt[(((size_t)l * RD + m) * RD + c) * 3 + j];
        else        v = Ws[(((size_t)l * RD + (m - 32)) * RD + c) * 3 + j];
        Wg[idx] = f2bf(v);
    } else if (idx < n1 + n2) {
        const int i2 = idx - n1;
        Wdb[i2] = f2bf(Wd[i2]);
    }
}

// ---------------- 7 fused layers (d=1..64), halo recompute, NO inter-block sync ----
// Each block stages rows [t0-128, t0+384) of x (fp32) in LDS double-buffer and
// runs layers l0..l0+6 locally. Owned rows [t0, t0+256) stay valid through all
// 7 layers (sum d = 127 <= 128). Out-of-[0,T) rows are pinned to 0 every layer
// (matches conv zero padding). Channel chunks (4 floats) stored at
// chunk ^ (row&7) to break the 128B-row bank aliasing (~2-way residual).
// Numerics identical to the unfused path: fp32 x chain, f2bf at MFMA inputs.
__global__ __launch_bounds__(512, 2)
void k_group7(const float* __restrict__ xin_g, float* __restrict__ xout_g,
              unsigned short* __restrict__ Gt,          // [NL][T][32]
              const unsigned short* __restrict__ WgAll, // [NL][64][96]
              const unsigned short* __restrict__ WdbAll,// [NL][32][32]
              const float* __restrict__ btAll,
              const float* __restrict__ bsAll,
              const float* __restrict__ bdAll,
              int l0)
{
    __shared__ float xs[2][GR * RD];            // 128 KB
    __shared__ unsigned short gtile[256 * RD];  // 16 KB

    const int tid = threadIdx.x;
    const int lane = tid & 63;
    const int w = tid >> 6;       // 0..7
    const int quad = lane >> 4;
    const int l16 = lane & 15;
    const int b = blockIdx.x;
    const int t0 = b * GC;
    const floatx4 vzero = {0.f, 0.f, 0.f, 0.f};

    // ---- initial fill: one row per thread (GR == blockDim) ----
    {
        const int e = tid;
        const int t = t0 - GH + e;
        float* dst = &xs[0][e * RD];
        if (t >= 0 && t < T_LEN) {
            const float* src = xin_g + (size_t)t * RD;
#pragma unroll
            for (int c = 0; c < 8; ++c)
                *reinterpret_cast<floatx4*>(&dst[(c ^ (e & 7)) * 4]) =
                    *reinterpret_cast<const floatx4*>(src + c * 4);
        } else {
#pragma unroll
            for (int c = 0; c < 8; ++c)
                *reinterpret_cast<floatx4*>(&dst[(c ^ (e & 7)) * 4]) = vzero;
        }
    }
    __syncthreads();

    int cur = 0;
    for (int i = 0; i < GNL; ++i) {
        const int d = 1 << i;
        const int l = l0 + i;
        const unsigned short* Wg = WgAll + (size_t)l * 64 * 96;
        const unsigned short* Wdb = WdbAll + (size_t)l * RD * RD;
        const float* btp = btAll + (size_t)l * RD;
        const float* bsp = bsAll + (size_t)l * RD;
        const float* bdp = bdAll + (size_t)l * RD;

        short8 afr[3][4];
#pragma unroll
        for (int j = 0; j < 3; ++j)
#pragma unroll
            for (int mt = 0; mt < 4; ++mt)
                afr[j][mt] = *reinterpret_cast<const short8*>(
                    Wg + (size_t)(mt * 16 + l16) * 96 + j * 32 + quad * 8);
        short8 ad[2];
#pragma unroll
        for (int mt = 0; mt < 2; ++mt)
            ad[mt] = *reinterpret_cast<const short8*>(
                Wdb + (size_t)(mt * 16 + l16) * RD + quad * 8);

        for (int rs = 0; rs < GR; rs += 256) {
            const int rloc = w * 32;

            // ---- phase A: gated convolution ----
            floatx4 acc[4][2];
#pragma unroll
            for (int mt = 0; mt < 4; ++mt)
#pragma unroll
                for (int nt = 0; nt < 2; ++nt) acc[mt][nt] = vzero;

#pragma unroll
            for (int nt = 0; nt < 2; ++nt) {
                const int e = rs + rloc + nt * 16 + l16;
#pragma unroll
                for (int j = 0; j < 3; ++j) {
                    const int et = e + (j - 1) * d;
                    short8 bb;
                    if (et >= 0 && et < GR) {
                        const float* srow = &xs[cur][et * RD];
                        const int sw = et & 7;
                        const floatx4 f0 = *reinterpret_cast<const floatx4*>(
                            &srow[((2 * quad) ^ sw) * 4]);
                        const floatx4 f1 = *reinterpret_cast<const floatx4*>(
                            &srow[(((2 * quad) + 1) ^ sw) * 4]);
#pragma unroll
                        for (int k2 = 0; k2 < 4; ++k2) {
                            bb[k2] = (short)f2bf(f0[k2]);
                            bb[4 + k2] = (short)f2bf(f1[k2]);
                        }
                    } else {
#pragma unroll
                        for (int k2 = 0; k2 < 8; ++k2) bb[k2] = 0;
                    }
#pragma unroll
                    for (int mt = 0; mt < 4; ++mt)
                        acc[mt][nt] = __builtin_amdgcn_mfma_f32_16x16x32_bf16(
                            afr[j][mt], bb, acc[mt][nt], 0, 0, 0);
                }
            }

            // ---- gate + gtile + Gt (owned rows only) ----
#pragma unroll
            for (int nt = 0; nt < 2; ++nt) {
                const int tloc = rloc + nt * 16 + l16;
                const int e = rs + tloc;
#pragma unroll
                for (int pair = 0; pair < 2; ++pair) {
                    const floatx4 bt4 = *reinterpret_cast<const floatx4*>(btp + pair * 16 + quad * 4);
                    const floatx4 bs4 = *reinterpret_cast<const floatx4*>(bsp + pair * 16 + quad * 4);
                    ushort4 u;
                    unsigned short us[4];
#pragma unroll
                    for (int r = 0; r < 4; ++r) {
                        const float a1 = acc[pair][nt][r] + bt4[r];
                        const float a2 = acc[2 + pair][nt][r] + bs4[r];
                        const float th = 1.f - __fdividef(2.f, __expf(2.f * a1) + 1.f);
                        const float sg = __fdividef(1.f, 1.f + __expf(-a2));
                        us[r] = f2bf(th * sg);
                    }
                    u.x = us[0]; u.y = us[1]; u.z = us[2]; u.w = us[3];
                    const int cbase = pair * 16 + quad * 4;
                    *reinterpret_cast<ushort4*>(&gtile[tloc * RD + cbase]) = u;
                    if (e >= GH && e < GH + GC) {
                        const int t = t0 + e - GH;
                        *reinterpret_cast<ushort4*>(
                            Gt + ((size_t)l * T_LEN + t) * RD + cbase) = u;
                    }
                }
            }

            __syncthreads();

            // ---- phase B: dense(1x1) + residual, write next buffer ----
#pragma unroll
            for (int nt = 0; nt < 2; ++nt) {
                const int tloc = rloc + nt * 16 + l16;
                const int e = rs + tloc;
                const int t = t0 + e - GH;
                const bool inT = (t >= 0 && t < T_LEN);
                const short8 bg = *reinterpret_cast<const short8*>(&gtile[tloc * RD + quad * 8]);
#pragma unroll
                for (int mt = 0; mt < 2; ++mt) {
                    const floatx4 a2v = __builtin_amdgcn_mfma_f32_16x16x32_bf16(ad[mt], bg, vzero, 0, 0, 0);
                    const int m = mt * 16 + quad * 4;
                    const int pos = ((4 * mt + quad) ^ (e & 7)) * 4;
                    const floatx4 bd4 = *reinterpret_cast<const floatx4*>(bdp + m);
                    const floatx4 xi = *reinterpret_cast<const floatx4*>(&xs[cur][e * RD + pos]);
                    floatx4 o;
#pragma unroll
                    for (int r = 0; r < 4; ++r)
                        o[r] = inT ? (a2v[r] + bd4[r] + xi[r]) : 0.f;
                    *reinterpret_cast<floatx4*>(&xs[cur ^ 1][e * RD + pos]) = o;
                    if (i == GNL - 1 && e >= GH && e < GH + GC)
                        *reinterpret_cast<floatx4*>(xout_g + (size_t)t * RD + m) = o;
                }
            }
            __syncthreads();
        }
        cur ^= 1;
    }
}

// ---------------- one residual layer via MFMA (d=128/256), 128 t per block ----
__global__ __launch_bounds__(256)
void k_layer_mfma(const float* __restrict__ xin,
                  float* __restrict__ xout,
                  unsigned short* __restrict__ Gt,      // [NL][T][32]
                  const unsigned short* __restrict__ Wg,   // [64][96] bf16
                  const unsigned short* __restrict__ Wdb,  // [32][32] bf16
                  const float* __restrict__ bt, const float* __restrict__ bs,
                  const float* __restrict__ bd, int d, int layer)
{
    __shared__ unsigned short gtile[128 * 32];  // 8 KB
    const int tid = threadIdx.x;
    const int lane = tid & 63;
    const int w = tid >> 6;
    const int quad = lane >> 4;
    const int l16 = lane & 15;
    const int tbase = blockIdx.x * 128 + w * 32;

    short8 afr[3][4];
#pragma unroll
    for (int j = 0; j < 3; ++j)
#pragma unroll
        for (int mt = 0; mt < 4; ++mt)
            afr[j][mt] = *reinterpret_cast<const short8*>(
                Wg + (size_t)(mt * 16 + l16) * 96 + j * 32 + quad * 8);

    floatx4 acc[4][2];
    const floatx4 vzero = {0.f, 0.f, 0.f, 0.f};
#pragma unroll
    for (int mt = 0; mt < 4; ++mt)
#pragma unroll
        for (int nt = 0; nt < 2; ++nt) acc[mt][nt] = vzero;

#pragma unroll
    for (int nt = 0; nt < 2; ++nt) {
        const int t = tbase + nt * 16 + l16;
#pragma unroll
        for (int j = 0; j < 3; ++j) {
            const int tt = t + (j - 1) * d;
            short8 b;
            if (tt >= 0 && tt < T_LEN) {
                const float* src = xin + (size_t)tt * RD + quad * 8;
                const floatx4 f0 = *reinterpret_cast<const floatx4*>(src);
                const floatx4 f1 = *reinterpret_cast<const floatx4*>(src + 4);
#pragma unroll
                for (int i = 0; i < 4; ++i) {
                    b[i] = (short)f2bf(f0[i]);
                    b[4 + i] = (short)f2bf(f1[i]);
                }
            } else {
#pragma unroll
                for (int i = 0; i < 8; ++i) b[i] = 0;
            }
#pragma unroll
            for (int mt = 0; mt < 4; ++mt)
                acc[mt][nt] = __builtin_amdgcn_mfma_f32_16x16x32_bf16(afr[j][mt], b, acc[mt][nt], 0, 0, 0);
        }
    }

#pragma unroll
    for (int nt = 0; nt < 2; ++nt) {
        const int t = tbase + nt * 16 + l16;
        const int tloc = w * 32 + nt * 16 + l16;
#pragma unroll
        for (int pair = 0; pair < 2; ++pair) {
            const floatx4 bt4 = *reinterpret_cast<const floatx4*>(bt + pair * 16 + quad * 4);
            const floatx4 bs4 = *reinterpret_cast<const floatx4*>(bs + pair * 16 + quad * 4);
            ushort4 u;
            unsigned short us[4];
#pragma unroll
            for (int r = 0; r < 4; ++r) {
                const float a1 = acc[pair][nt][r] + bt4[r];
                const float a2 = acc[2 + pair][nt][r] + bs4[r];
                const float th = 1.f - __fdividef(2.f, __expf(2.f * a1) + 1.f);
                const float sg = __fdividef(1.f, 1.f + __expf(-a2));
                us[r] = f2bf(th * sg);
            }
            u.x = us[0]; u.y = us[1]; u.z = us[2]; u.w = us[3];
            const int cbase = pair * 16 + quad * 4;
            *reinterpret_cast<ushort4*>(&gtile[tloc * 32 + cbase]) = u;
            *reinterpret_cast<ushort4*>(
                Gt + ((size_t)layer * T_LEN + t) * RD + cbase) = u;
        }
    }

    __syncthreads();

    short8 ad[2];
#pragma unroll
    for (int mt = 0; mt < 2; ++mt)
        ad[mt] = *reinterpret_cast<const short8*>(Wdb + (size_t)(mt * 16 + l16) * 32 + quad * 8);

#pragma unroll
    for (int nt = 0; nt < 2; ++nt) {
        const int t = tbase + nt * 16 + l16;
        const int tloc = w * 32 + nt * 16 + l16;
        const short8 bg = *reinterpret_cast<const short8*>(&gtile[tloc * 32 + quad * 8]);
#pragma unroll
        for (int mt = 0; mt < 2; ++mt) {
            const floatx4 a2 = __builtin_amdgcn_mfma_f32_16x16x32_bf16(ad[mt], bg, vzero, 0, 0, 0);
            const int m = mt * 16 + quad * 4;
            const floatx4 bd4 = *reinterpret_cast<const floatx4*>(bd + m);
            const floatx4 xi = *reinterpret_cast<const floatx4*>(xin + (size_t)t * RD + m);
            floatx4 o;
            o[0] = a2[0] + bd4[0] + xi[0];
            o[1] = a2[1] + bd4[1] + xi[1];
            o[2] = a2[2] + bd4[2] + xi[2];
            o[3] = a2[3] + bd4[3] + xi[3];
            *reinterpret_cast<floatx4*>(xout + (size_t)t * RD + m) = o;
        }
    }
}

// ---------------- Wcomb (chunk-major [27][512][32]) ----------------
__global__ __launch_bounds__(256)
void k_wcomb(const float* __restrict__ Wp1, const float* __restrict__ Wskip,
             unsigned short* __restrict__ Wcomb)
{
    const int idx = blockIdx.x * 256 + threadIdx.x;
    if (idx >= SD * KTOT) return;
    const int m = idx / KTOT;
    const int k = idx % KTOT;
    const int l = k / RD;
    const int c = k % RD;
    const float* wp1r = Wp1 + (size_t)m * SD;
    const float* wsk = Wskip + (size_t)l * SD * RD + c;
    float acc = 0.f;
    for (int j = 0; j < SD; ++j) acc += wp1r[j] * wsk[(size_t)j * RD];
    Wcomb[((size_t)l * SD + m) * RD + c] = f2bf(acc);
}

// ---------------- hbias ----------------
__global__ __launch_bounds__(512)
void k_hbias(const float* __restrict__ Wp1, const float* __restrict__ bp1,
             const float* __restrict__ bskip, float* __restrict__ hbias)
{
    __shared__ float sb[SD];
    const int tid = threadIdx.x;
    float s = 0.f;
    for (int l = 0; l < NL; ++l) s += bskip[l * SD + tid];
    sb[tid] = s;
    __syncthreads();
    float acc = bp1[tid];
    const float* r = Wp1 + (size_t)tid * SD;
    for (int j = 0; j < SD; ++j) acc += r[j] * sb[j];
    hbias[tid] = acc;
}

// ---------------- fp32 -> bf16 cast ----------------
__global__ __launch_bounds__(256)
void k_cvt(const float* __restrict__ src, unsigned short* __restrict__ dst, int n)
{
    const int i = blockIdx.x * 256 + threadIdx.x;
    if (i < n) dst[i] = f2bf(src[i]);
}

// ---------------- GEMM1: ht = relu(hbias + Wcomb@Gt) ----------------
__global__ __launch_bounds__(256)
void k_gemm1(const unsigned short* __restrict__ A,   // Wcomb [27][512][32]
             const unsigned short* __restrict__ B,   // Gt [27][T][32]
             const float* __restrict__ hbias,
             unsigned short* __restrict__ ht)        // [16][T][32]
{
    __shared__ unsigned short ldsA[128 * 32];  // 8 KB
    __shared__ unsigned short ldsB[128 * 32];  // 8 KB
    const int tid = threadIdx.x;
    const int lane = tid & 63;
    const int w = tid >> 6;
    const int wm = w & 1;
    const int wn = w >> 1;
    const int quad = lane >> 4;
    const int l16 = lane & 15;

    const int g = blockIdx.x;
    const int m0 = ((g >> 3) & 3) * 128;
    const int n0 = ((g & 7) + 8 * (g >> 5)) * 128;

    const int r4 = lane >> 2;
    const int c4 = lane & 3;
    const int srcc = c4 ^ ((r4 >> 1) & 3);   // permuted global chunk
    const int swz = (l16 >> 1) & 3;          // reader-side key

    floatx4 acc[4][4];
    const floatx4 vzero = {0.f, 0.f, 0.f, 0.f};
#pragma unroll
    for (int mt = 0; mt < 4; ++mt)
#pragma unroll
        for (int nt = 0; nt < 4; ++nt) acc[mt][nt] = vzero;

    const unsigned short* pA = A + (size_t)(m0 + r4) * RD + srcc * 8;
    const unsigned short* pB = B + (size_t)(n0 + r4) * RD + srcc * 8;

    for (int kc = 0; kc < KTOT / 32; ++kc) {
#pragma unroll
        for (int c = 0; c < 2; ++c) {
            const int row = w * 32 + c * 16;
            gload_lds16(pA + ((size_t)kc * SD + row) * RD, &ldsA[(size_t)row * 32]);
            gload_lds16(pB + ((size_t)kc * T_LEN + row) * RD, &ldsB[(size_t)row * 32]);
        }
        __syncthreads();

        short8 afr[4], bfr[4];
#pragma unroll
        for (int mt = 0; mt < 4; ++mt)
            afr[mt] = *reinterpret_cast<const short8*>(
                &ldsA[(wm * 64 + mt * 16 + l16) * 32 + (quad ^ swz) * 8]);
#pragma unroll
        for (int nt = 0; nt < 4; ++nt)
            bfr[nt] = *reinterpret_cast<const short8*>(
                &ldsB[(wn * 64 + nt * 16 + l16) * 32 + (quad ^ swz) * 8]);
#pragma unroll
        for (int mt = 0; mt < 4; ++mt)
#pragma unroll
            for (int nt = 0; nt < 4; ++nt)
                acc[mt][nt] = __builtin_amdgcn_mfma_f32_16x16x32_bf16(afr[mt], bfr[nt], acc[mt][nt], 0, 0, 0);
        __syncthreads();
    }

#pragma unroll
    for (int mt = 0; mt < 4; ++mt) {
        const int m = m0 + wm * 64 + mt * 16 + quad * 4;
        const floatx4 hb = *reinterpret_cast<const floatx4*>(hbias + m);
        const size_t chunkbase = (size_t)(m >> 5) * T_LEN;
        const int mc = m & 31;
#pragma unroll
        for (int nt = 0; nt < 4; ++nt) {
            const int t = n0 + wn * 64 + nt * 16 + l16;
            ushort4 st;
            float v;
            v = acc[mt][nt][0] + hb[0]; st.x = f2bf(v > 0.f ? v : 0.f);
            v = acc[mt][nt][1] + hb[1]; st.y = f2bf(v > 0.f ? v : 0.f);
            v = acc[mt][nt][2] + hb[2]; st.z = f2bf(v > 0.f ? v : 0.f);
            v = acc[mt][nt][3] + hb[3]; st.w = f2bf(v > 0.f ? v : 0.f);
            *reinterpret_cast<ushort4*>(ht + (chunkbase + t) * RD + mc) = st;
        }
    }
}

// ---------------- GEMM2 + fused log_softmax, LDS-staged B ----------------
__global__ __launch_bounds__(256)
void k_gemm2_lsm(const unsigned short* __restrict__ A,  // Wp2b [256][512] bf16
                 const unsigned short* __restrict__ B,  // ht [16][T][32] bf16
                 const float* __restrict__ bp2,
                 float* __restrict__ out)               // [256][T] fp32
{
    __shared__ unsigned short ldsB[64 * 32];  // 4 KB
    __shared__ float redmax[4 * 16 * 16];
    __shared__ float redsum[4 * 16 * 16];
    const int tid = threadIdx.x;
    const int lane = tid & 63;
    const int w = tid >> 6;   // 0..3 = m-slice
    const int quad = lane >> 4;
    const int l16 = lane & 15;
    const int m0 = w * 64;
    const int n0 = blockIdx.x * 64;

    const int r4 = lane >> 2;
    const int c4 = lane & 3;
    const int srcc = c4 ^ ((r4 >> 1) & 3);
    const int swz = (l16 >> 1) & 3;

    const unsigned short* ab[4];
#pragma unroll
    for (int mt = 0; mt < 4; ++mt)
        ab[mt] = A + (size_t)(m0 + mt * 16 + l16) * SD + quad * 8;

    const unsigned short* pB = B + (size_t)(n0 + w * 16 + r4) * RD + srcc * 8;

    floatx4 acc[4][4];
    const floatx4 vzero = {0.f, 0.f, 0.f, 0.f};
#pragma unroll
    for (int mt = 0; mt < 4; ++mt)
#pragma unroll
        for (int nt = 0; nt < 4; ++nt) acc[mt][nt] = vzero;

    for (int kc = 0; kc < SD / 32; ++kc) {
        const int k0 = kc * 32;
        gload_lds16(pB + (size_t)kc * T_LEN * RD, &ldsB[(size_t)(w * 16) * 32]);
        short8 afr[4];
#pragma unroll
        for (int mt = 0; mt < 4; ++mt)
            afr[mt] = *reinterpret_cast<const short8*>(ab[mt] + k0);
        __syncthreads();

        short8 bfr[4];
#pragma unroll
        for (int nt = 0; nt < 4; ++nt)
            bfr[nt] = *reinterpret_cast<const short8*>(
                &ldsB[(nt * 16 + l16) * 32 + (quad ^ swz) * 8]);
#pragma unroll
        for (int mt = 0; mt < 4; ++mt)
#pragma unroll
            for (int nt = 0; nt < 4; ++nt)
                acc[mt][nt] = __builtin_amdgcn_mfma_f32_16x16x32_bf16(
                    afr[mt], bfr[nt], acc[mt][nt], 0, 0, 0);
        __syncthreads();
    }

#pragma unroll
    for (int mt = 0; mt < 4; ++mt) {
        const int mb = m0 + mt * 16 + quad * 4;
        const floatx4 bz = *reinterpret_cast<const floatx4*>(bp2 + mb);
#pragma unroll
        for (int nt = 0; nt < 4; ++nt)
#pragma unroll
            for (int j = 0; j < 4; ++j) acc[mt][nt][j] += bz[j];
    }

#pragma unroll
    for (int nt = 0; nt < 4; ++nt) {
        float lm = -1e30f;
#pragma unroll
        for (int mt = 0; mt < 4; ++mt)
#pragma unroll
            for (int j = 0; j < 4; ++j) lm = fmaxf(lm, acc[mt][nt][j]);
        redmax[nt * 256 + l16 * 16 + w * 4 + quad] = lm;
    }
    __syncthreads();

    float lse[4];
#pragma unroll
    for (int nt = 0; nt < 4; ++nt) {
        float gm = -1e30f;
#pragma unroll
        for (int i = 0; i < 16; ++i) gm = fmaxf(gm, redmax[nt * 256 + l16 * 16 + i]);
        float ls = 0.f;
#pragma unroll
        for (int mt = 0; mt < 4; ++mt)
#pragma unroll
            for (int j = 0; j < 4; ++j) ls += __expf(acc[mt][nt][j] - gm);
        redsum[nt * 256 + l16 * 16 + w * 4 + quad] = ls;
        lse[nt] = gm;
    }
    __syncthreads();

#pragma unroll
    for (int nt = 0; nt < 4; ++nt) {
        float tot = 0.f;
#pragma unroll
        for (int i = 0; i < 16; ++i) tot += redsum[nt * 256 + l16 * 16 + i];
        lse[nt] = lse[nt] + __logf(tot);
    }

#pragma unroll
    for (int mt = 0; mt < 4; ++mt) {
        const int mb = m0 + mt * 16 + quad * 4;
#pragma unroll
        for (int nt = 0; nt < 4; ++nt) {
            const int t = n0 + nt * 16 + l16;
#pragma unroll
            for (int j = 0; j < 4; ++j)
                out[(size_t)(mb + j) * T_LEN + t] = acc[mt][nt][j] - lse[nt];
        }
    }
}

extern "C" void kernel_launch(void* const* d_in, const int* in_sizes, int n_in,
                              void* d_out, int out_size, void* d_ws, size_t ws_size,
                              hipStream_t stream)
{
    (void)in_sizes; (void)n_in; (void)out_size; (void)ws_size;
    const float* x     = (const float*)d_in[0];
    const float* Wc    = (const float*)d_in[1];
    const float* bc    = (const float*)d_in[2];
    const float* Wt    = (const float*)d_in[3];
    const float* bt    = (const float*)d_in[4];
    const float* Ws    = (const float*)d_in[5];
    const float* bs    = (const float*)d_in[6];
    const float* Wskip = (const float*)d_in[7];
    const float* bskip = (const float*)d_in[8];
    const float* Wd    = (const float*)d_in[9];
    const float* bd    = (const float*)d_in[10];
    const float* Wp1   = (const float*)d_in[11];
    const float* bp1   = (const float*)d_in[12];
    const float* Wp2   = (const float*)d_in[13];
    const float* bp2   = (const float*)d_in[14];
    float* out = (float*)d_out;

    char* p = (char*)d_ws;
    unsigned short* Gt = (unsigned short*)p;    p += (size_t)T_LEN * KTOT * 2;   // 226.5 MB, [27][T][32]
    unsigned short* ht = (unsigned short*)p;    p += (size_t)T_LEN * SD * 2;     // 134 MB, [16][T][32]
    unsigned short* Wcomb = (unsigned short*)p; p += (size_t)SD * KTOT * 2;
    unsigned short* Wp2b = (unsigned short*)p;  p += (size_t)QD * SD * 2;
    unsigned short* Wg = (unsigned short*)p;    p += (size_t)NL * 64 * 96 * 2;
    unsigned short* Wdb = (unsigned short*)p;   p += (size_t)NL * RD * RD * 2;
    float* hbias = (float*)p;                   p += (size_t)SD * 4;

    // x ping-pong buffers alias the ht region (dead before gemm1 writes ht)
    char* q = (char*)ht;
    float* xa = (float*)q;                      q += (size_t)T_LEN * RD * 4;
    float* xb = (float*)q;                      q += (size_t)T_LEN * RD * 4;

    k_wcomb<<<(SD * KTOT + 255) / 256, 256, 0, stream>>>(Wp1, Wskip, Wcomb);
    k_hbias<<<1, 512, 0, stream>>>(Wp1, bp1, bskip, hbias);
    k_cvt<<<(QD * SD + 255) / 256, 256, 0, stream>>>(Wp2, Wp2b, QD * SD);
    {
        const int nprep = NL * 64 * 96 + NL * RD * RD;
        k_wprep<<<(nprep + 255) / 256, 256, 0, stream>>>(Wt, Ws, Wd, Wg, Wdb);
    }
    k_conv_init<<<T_LEN / 256, 256, 0, stream>>>(x, Wc, bc, xa);

    const float* cur = xa;
    float* nxt = xb;
    for (int s = 0; s < 3; ++s) {
        // layers 9s .. 9s+6 (d = 1..64) fused
        k_group7<<<T_LEN / GC, 512, 0, stream>>>(
            cur, nxt, Gt, Wg, Wdb, bt, bs, bd, 9 * s);
        { float* tf = (float*)cur; cur = nxt; nxt = tf; }
        // layer 9s+7 (d = 128)
        k_layer_mfma<<<T_LEN / 128, 256, 0, stream>>>(
            cur, nxt, Gt,
            Wg + (size_t)(9 * s + 7) * 64 * 96,
            Wdb + (size_t)(9 * s + 7) * RD * RD,
            bt + (size_t)(9 * s + 7) * RD,
            bs + (size_t)(9 * s + 7) * RD,
            bd + (size_t)(9 * s + 7) * RD,
            128, 9 * s + 7);
        { float* tf = (float*)cur; cur = nxt; nxt = tf; }
        // layer 9s+8 (d = 256)
        k_layer_mfma<<<T_LEN / 128, 256, 0, stream>>>(
            cur, nxt, Gt,
            Wg + (size_t)(9 * s + 8) * 64 * 96,
            Wdb + (size_t)(9 * s + 8) * RD * RD,
            bt + (size_t)(9 * s + 8) * RD,
            bs + (size_t)(9 * s + 8) * RD,
            bd + (size_t)(9 * s + 8) * RD,
            256, 9 * s + 8);
        { float* tf = (float*)cur; cur = nxt; nxt = tf; }
    }

    k_gemm1<<<4 * (T_LEN / 128), 256, 0, stream>>>(Wcomb, Gt, hbias, ht);
    k_gemm2_lsm<<<T_LEN / 64, 256, 0, stream>>>(Wp2b, ht, bp2, out);
}

// Round 5
// 1015.788 us; speedup vs baseline: 2.5228x; 1.0285x over previous
//
#include <hip/hip_runtime.h>

#define T_LEN 131072
#define RD 32
#define SD 512
#define QD 256
#define NL 27
#define KTOT (NL * RD)   // 864
#define GPAD 256         // guard rows (zeros) on each side of x buffers

typedef __attribute__((ext_vector_type(8))) short short8;
typedef __attribute__((ext_vector_type(4))) float floatx4;

__device__ __forceinline__ unsigned short f2bf(float f) {
    union { float f; unsigned int i; } v; v.f = f;
    unsigned int r = v.i + 0x7fffu + ((v.i >> 16) & 1u);  // RNE
    return (unsigned short)(r >> 16);
}

__device__ __forceinline__ void gload_lds16(const void* g, void* l) {
    __builtin_amdgcn_global_load_lds(
        (const __attribute__((address_space(1))) unsigned int*)g,
        (__attribute__((address_space(3))) unsigned int*)l, 16, 0, 0);
}

// ---------------- initial conv: [1,T] -> [T][32] fp32 + bf16; zero guards ----------------
__global__ __launch_bounds__(256)
void k_conv_init(const float* __restrict__ x, const float* __restrict__ Wc,
                 const float* __restrict__ bc,
                 float* __restrict__ xaG, unsigned short* __restrict__ xabG,
                 float* __restrict__ xbG, unsigned short* __restrict__ xbbG)
{
    const int gid = blockIdx.x * 256 + threadIdx.x;

    // zero the 4 guard regions (pre/post of xa and xb), fp32 + bf16 mirrors
    if (gid < 4 * GPAD * RD) {
        const int region = gid >> 13;           // GPAD*RD = 8192
        const int idx = gid & (GPAD * RD - 1);
        float* fg; unsigned short* hg;
        const size_t post = (size_t)(GPAD + T_LEN) * RD;
        switch (region) {
            case 0:  fg = xaG;        hg = xabG;        break;
            case 1:  fg = xaG + post; hg = xabG + post; break;
            case 2:  fg = xbG;        hg = xbbG;        break;
            default: fg = xbG + post; hg = xbbG + post; break;
        }
        fg[idx] = 0.f;
        hg[idx] = 0;
    }

    const int t = gid;
    const float xm = (t > 0) ? x[t - 1] : 0.f;
    const float x0 = x[t];
    const float xp = (t < T_LEN - 1) ? x[t + 1] : 0.f;
    float* row = xaG + (size_t)(GPAD + t) * RD;
    unsigned short* rowb = xabG + (size_t)(GPAD + t) * RD;
#pragma unroll
    for (int o = 0; o < RD; ++o) {
        const float v = bc[o] + Wc[o * 3 + 0] * xm + Wc[o * 3 + 1] * x0 + Wc[o * 3 + 2] * xp;
        row[o] = v;
        rowb[o] = f2bf(v);
    }
}

// ---------------- weight prep ----------------
__global__ __launch_bounds__(256)
void k_wprep(const float* __restrict__ Wt, const float* __restrict__ Ws,
             const float* __restrict__ Wd,
             unsigned short* __restrict__ Wg, unsigned short* __restrict__ Wdb)
{
    const int idx = blockIdx.x * 256 + threadIdx.x;
    const int n1 = NL * 64 * 96;
    const int n2 = NL * RD * RD;
    if (idx < n1) {
        const int l = idx / (64 * 96);
        const int rem = idx % (64 * 96);
        const int m = rem / 96;
        const int k = rem % 96;
        const int j = k / 32;
        const int c = k % 32;
        float v;
        if (m < 32) v = Wt[(((size_t)l * RD + m) * RD + c) * 3 + j];
        else        v = Ws[(((size_t)l * RD + (m - 32)) * RD + c) * 3 + j];
        Wg[idx] = f2bf(v);
    } else if (idx < n1 + n2) {
        const int i2 = idx - n1;
        Wdb[i2] = f2bf(Wd[i2]);
    }
}

// ---------------- one residual layer: per-wave async-staged, NO barriers ----------------
// Each wave owns 32 t-rows. It DMAs (global_load_lds, zero VGPR cost):
//   - 3 bf16 tap bands   (its 32 rows each)  -> bandsL, XOR-swizzled source
//   - its 32 fp32 center rows (residual)     -> centerL, XOR-swizzled source
// then waits vmcnt(4) (bands ready, center in flight), computes phase A from
// LDS (1 ds_read_b128 per tap, no f2bf), waits vmcnt(0), gate -> gtileL
// (wave-private rows) + Gt store, phase B (dense+residual) from LDS.
// Guard zones make all tap addresses valid; zeros == conv zero-padding.
// Swizzles are XOR involutions applied on DMA *source* and ds_read (rule:
// both-sides-or-neither with global_load_lds).
__global__ __launch_bounds__(256, 3)
void k_layer_stage(const float* __restrict__ xin,          // guarded base + GPAD rows
                   const unsigned short* __restrict__ xinb,
                   float* __restrict__ xout,
                   unsigned short* __restrict__ xoutb,
                   unsigned short* __restrict__ Gt,        // [NL][T][32]
                   const unsigned short* __restrict__ Wg,  // [64][96] bf16
                   const unsigned short* __restrict__ Wdb, // [32][32] bf16
                   const float* __restrict__ bt, const float* __restrict__ bs,
                   const float* __restrict__ bd, int d, int layer)
{
    __shared__ unsigned short bandsL[3][128 * 32];  // 24 KB bf16 taps
    __shared__ float centerL[128 * 32];             // 16 KB fp32 residual
    __shared__ unsigned short gtileL[128 * 32];     // 8 KB gate bf16

    const int tid = threadIdx.x;
    const int lane = tid & 63;
    const int w = tid >> 6;
    const int quad = lane >> 4;
    const int l16 = lane & 15;
    const int rbase = w * 32;                       // block-relative rows of this wave
    const bool last = (layer == NL - 1);
    const floatx4 vzero = {0.f, 0.f, 0.f, 0.f};

    // per-lane DMA source decomposition
    const int r16c = lane >> 2;                     // row within 16-row chunk (bf16)
    const int scB = (lane & 3) ^ ((lane >> 3) & 3); // pre-swizzled 16B col (bf16 row=64B)
    const int r8c = lane >> 3;                      // row within 8-row chunk (fp32)
    const int scC = (lane & 7) ^ r8c;               // pre-swizzled 16B col (fp32 row=128B)
    const long long gbase = (long long)blockIdx.x * 128 + rbase;

    // ---- issue band DMAs (6) ----
#pragma unroll
    for (int j = 0; j < 3; ++j) {
        const long long b0 = gbase + (long long)(j - 1) * d;
#pragma unroll
        for (int i = 0; i < 2; ++i)
            gload_lds16(xinb + (b0 + i * 16 + r16c) * RD + scB * 8,
                        &bandsL[j][(rbase + i * 16) * 32]);
    }
    // ---- issue center DMAs (4) + counted wait ----
    if (!last) {
#pragma unroll
        for (int i = 0; i < 4; ++i)
            gload_lds16(xin + (gbase + i * 8 + r8c) * RD + scC * 4,
                        &centerL[(rbase + i * 8) * 32]);
        asm volatile("s_waitcnt vmcnt(4)" ::: "memory");  // bands done, center in flight
    } else {
        asm volatile("s_waitcnt vmcnt(0)" ::: "memory");
    }

    // ---- per-layer weight fragments ----
    short8 afr[3][4];
#pragma unroll
    for (int j = 0; j < 3; ++j)
#pragma unroll
        for (int mt = 0; mt < 4; ++mt)
            afr[j][mt] = *reinterpret_cast<const short8*>(
                Wg + (size_t)(mt * 16 + l16) * 96 + j * 32 + quad * 8);

    // ---- phase A: gated conv from LDS bands ----
    floatx4 acc[4][2];
#pragma unroll
    for (int mt = 0; mt < 4; ++mt)
#pragma unroll
        for (int nt = 0; nt < 2; ++nt) acc[mt][nt] = vzero;

#pragma unroll
    for (int nt = 0; nt < 2; ++nt) {
        const int rloc = rbase + nt * 16 + l16;
        const int key2 = (rloc >> 1) & 3;
#pragma unroll
        for (int j = 0; j < 3; ++j) {
            const short8 bb = *reinterpret_cast<const short8*>(
                &bandsL[j][rloc * 32 + ((quad ^ key2) * 8)]);
#pragma unroll
            for (int mt = 0; mt < 4; ++mt)
                acc[mt][nt] = __builtin_amdgcn_mfma_f32_16x16x32_bf16(
                    afr[j][mt], bb, acc[mt][nt], 0, 0, 0);
        }
    }

    if (!last) asm volatile("s_waitcnt vmcnt(0)" ::: "memory");  // center ready

    // ---- gate + gtile (wave-private) + Gt store ----
#pragma unroll
    for (int nt = 0; nt < 2; ++nt) {
        const int rloc = rbase + nt * 16 + l16;
        const int key2 = (rloc >> 1) & 3;
        const long long t = (long long)blockIdx.x * 128 + rloc;
#pragma unroll
        for (int pair = 0; pair < 2; ++pair) {
            const floatx4 bt4 = *reinterpret_cast<const floatx4*>(bt + pair * 16 + quad * 4);
            const floatx4 bs4 = *reinterpret_cast<const floatx4*>(bs + pair * 16 + quad * 4);
            ushort4 u;
            unsigned short us[4];
#pragma unroll
            for (int r = 0; r < 4; ++r) {
                const float a1 = acc[pair][nt][r] + bt4[r];
                const float a2 = acc[2 + pair][nt][r] + bs4[r];
                const float th = 1.f - __fdividef(2.f, __expf(2.f * a1) + 1.f);
                const float sg = __fdividef(1.f, 1.f + __expf(-a2));
                us[r] = f2bf(th * sg);
            }
            u.x = us[0]; u.y = us[1]; u.z = us[2]; u.w = us[3];
            const int cbase = pair * 16 + quad * 4;
            if (!last) {
                const int colS = (pair * 2 + (quad >> 1)) ^ key2;
                *reinterpret_cast<ushort4*>(
                    &gtileL[rloc * 32 + colS * 8 + (quad & 1) * 4]) = u;
            }
            *reinterpret_cast<ushort4*>(
                Gt + ((size_t)layer * T_LEN + t) * RD + cbase) = u;
        }
    }

    // ---- phase B: dense(1x1) + residual from LDS (skipped on dead layer 26) ----
    if (!last) {
        short8 ad[2];
#pragma unroll
        for (int mt = 0; mt < 2; ++mt)
            ad[mt] = *reinterpret_cast<const short8*>(
                Wdb + (size_t)(mt * 16 + l16) * RD + quad * 8);

#pragma unroll
        for (int nt = 0; nt < 2; ++nt) {
            const int rloc = rbase + nt * 16 + l16;
            const int key2 = (rloc >> 1) & 3;
            const long long t = (long long)blockIdx.x * 128 + rloc;
            const short8 bg = *reinterpret_cast<const short8*>(
                &gtileL[rloc * 32 + ((quad ^ key2) * 8)]);
#pragma unroll
            for (int mt = 0; mt < 2; ++mt) {
                const floatx4 a2v = __builtin_amdgcn_mfma_f32_16x16x32_bf16(
                    ad[mt], bg, vzero, 0, 0, 0);
                const int m = mt * 16 + quad * 4;
                const int c16 = (mt * 4 + quad) ^ (rloc & 7);
                const floatx4 xi = *reinterpret_cast<const floatx4*>(
                    &centerL[rloc * 32 + c16 * 4]);
                const floatx4 bd4 = *reinterpret_cast<const floatx4*>(bd + m);
                floatx4 o;
                ushort4 ob;
                o[0] = a2v[0] + bd4[0] + xi[0]; ob.x = f2bf(o[0]);
                o[1] = a2v[1] + bd4[1] + xi[1]; ob.y = f2bf(o[1]);
                o[2] = a2v[2] + bd4[2] + xi[2]; ob.z = f2bf(o[2]);
                o[3] = a2v[3] + bd4[3] + xi[3]; ob.w = f2bf(o[3]);
                *reinterpret_cast<floatx4*>(xout + (size_t)t * RD + m) = o;
                *reinterpret_cast<ushort4*>(xoutb + (size_t)t * RD + m) = ob;
            }
        }
    }
}

// ---------------- Wcomb (chunk-major [27][512][32]) ----------------
__global__ __launch_bounds__(256)
void k_wcomb(const float* __restrict__ Wp1, const float* __restrict__ Wskip,
             unsigned short* __restrict__ Wcomb)
{
    const int idx = blockIdx.x * 256 + threadIdx.x;
    if (idx >= SD * KTOT) return;
    const int m = idx / KTOT;
    const int k = idx % KTOT;
    const int l = k / RD;
    const int c = k % RD;
    const float* wp1r = Wp1 + (size_t)m * SD;
    const float* wsk = Wskip + (size_t)l * SD * RD + c;
    float acc = 0.f;
    for (int j = 0; j < SD; ++j) acc += wp1r[j] * wsk[(size_t)j * RD];
    Wcomb[((size_t)l * SD + m) * RD + c] = f2bf(acc);
}

// ---------------- hbias ----------------
__global__ __launch_bounds__(512)
void k_hbias(const float* __restrict__ Wp1, const float* __restrict__ bp1,
             const float* __restrict__ bskip, float* __restrict__ hbias)
{
    __shared__ float sb[SD];
    const int tid = threadIdx.x;
    float s = 0.f;
    for (int l = 0; l < NL; ++l) s += bskip[l * SD + tid];
    sb[tid] = s;
    __syncthreads();
    float acc = bp1[tid];
    const float* r = Wp1 + (size_t)tid * SD;
    for (int j = 0; j < SD; ++j) acc += r[j] * sb[j];
    hbias[tid] = acc;
}

// ---------------- fp32 -> bf16 cast ----------------
__global__ __launch_bounds__(256)
void k_cvt(const float* __restrict__ src, unsigned short* __restrict__ dst, int n)
{
    const int i = blockIdx.x * 256 + threadIdx.x;
    if (i < n) dst[i] = f2bf(src[i]);
}

// ---------------- GEMM1: ht = relu(hbias + Wcomb@Gt) ----------------
__global__ __launch_bounds__(256)
void k_gemm1(const unsigned short* __restrict__ A,   // Wcomb [27][512][32]
             const unsigned short* __restrict__ B,   // Gt [27][T][32]
             const float* __restrict__ hbias,
             unsigned short* __restrict__ ht)        // [16][T][32]
{
    __shared__ unsigned short ldsA[128 * 32];  // 8 KB
    __shared__ unsigned short ldsB[128 * 32];  // 8 KB
    const int tid = threadIdx.x;
    const int lane = tid & 63;
    const int w = tid >> 6;
    const int wm = w & 1;
    const int wn = w >> 1;
    const int quad = lane >> 4;
    const int l16 = lane & 15;

    const int g = blockIdx.x;
    const int m0 = ((g >> 3) & 3) * 128;
    const int n0 = ((g & 7) + 8 * (g >> 5)) * 128;

    const int r4 = lane >> 2;
    const int c4 = lane & 3;
    const int srcc = c4 ^ ((r4 >> 1) & 3);   // permuted global chunk
    const int swz = (l16 >> 1) & 3;          // reader-side key

    floatx4 acc[4][4];
    const floatx4 vzero = {0.f, 0.f, 0.f, 0.f};
#pragma unroll
    for (int mt = 0; mt < 4; ++mt)
#pragma unroll
        for (int nt = 0; nt < 4; ++nt) acc[mt][nt] = vzero;

    const unsigned short* pA = A + (size_t)(m0 + r4) * RD + srcc * 8;
    const unsigned short* pB = B + (size_t)(n0 + r4) * RD + srcc * 8;

    for (int kc = 0; kc < KTOT / 32; ++kc) {
#pragma unroll
        for (int c = 0; c < 2; ++c) {
            const int row = w * 32 + c * 16;
            gload_lds16(pA + ((size_t)kc * SD + row) * RD, &ldsA[(size_t)row * 32]);
            gload_lds16(pB + ((size_t)kc * T_LEN + row) * RD, &ldsB[(size_t)row * 32]);
        }
        __syncthreads();

        short8 afr[4], bfr[4];
#pragma unroll
        for (int mt = 0; mt < 4; ++mt)
            afr[mt] = *reinterpret_cast<const short8*>(
                &ldsA[(wm * 64 + mt * 16 + l16) * 32 + (quad ^ swz) * 8]);
#pragma unroll
        for (int nt = 0; nt < 4; ++nt)
            bfr[nt] = *reinterpret_cast<const short8*>(
                &ldsB[(wn * 64 + nt * 16 + l16) * 32 + (quad ^ swz) * 8]);
#pragma unroll
        for (int mt = 0; mt < 4; ++mt)
#pragma unroll
            for (int nt = 0; nt < 4; ++nt)
                acc[mt][nt] = __builtin_amdgcn_mfma_f32_16x16x32_bf16(afr[mt], bfr[nt], acc[mt][nt], 0, 0, 0);
        __syncthreads();
    }

#pragma unroll
    for (int mt = 0; mt < 4; ++mt) {
        const int m = m0 + wm * 64 + mt * 16 + quad * 4;
        const floatx4 hb = *reinterpret_cast<const floatx4*>(hbias + m);
        const size_t chunkbase = (size_t)(m >> 5) * T_LEN;
        const int mc = m & 31;
#pragma unroll
        for (int nt = 0; nt < 4; ++nt) {
            const int t = n0 + wn * 64 + nt * 16 + l16;
            ushort4 st;
            float v;
            v = acc[mt][nt][0] + hb[0]; st.x = f2bf(v > 0.f ? v : 0.f);
            v = acc[mt][nt][1] + hb[1]; st.y = f2bf(v > 0.f ? v : 0.f);
            v = acc[mt][nt][2] + hb[2]; st.z = f2bf(v > 0.f ? v : 0.f);
            v = acc[mt][nt][3] + hb[3]; st.w = f2bf(v > 0.f ? v : 0.f);
            *reinterpret_cast<ushort4*>(ht + (chunkbase + t) * RD + mc) = st;
        }
    }
}

// ---------------- GEMM2 + fused log_softmax, LDS-staged B ----------------
__global__ __launch_bounds__(256)
void k_gemm2_lsm(const unsigned short* __restrict__ A,  // Wp2b [256][512] bf16
                 const unsigned short* __restrict__ B,  // ht [16][T][32] bf16
                 const float* __restrict__ bp2,
                 float* __restrict__ out)               // [256][T] fp32
{
    __shared__ unsigned short ldsB[64 * 32];  // 4 KB
    __shared__ float redmax[4 * 16 * 16];
    __shared__ float redsum[4 * 16 * 16];
    const int tid = threadIdx.x;
    const int lane = tid & 63;
    const int w = tid >> 6;   // 0..3 = m-slice
    const int quad = lane >> 4;
    const int l16 = lane & 15;
    const int m0 = w * 64;
    const int n0 = blockIdx.x * 64;

    const int r4 = lane >> 2;
    const int c4 = lane & 3;
    const int srcc = c4 ^ ((r4 >> 1) & 3);
    const int swz = (l16 >> 1) & 3;

    const unsigned short* ab[4];
#pragma unroll
    for (int mt = 0; mt < 4; ++mt)
        ab[mt] = A + (size_t)(m0 + mt * 16 + l16) * SD + quad * 8;

    const unsigned short* pB = B + (size_t)(n0 + w * 16 + r4) * RD + srcc * 8;

    floatx4 acc[4][4];
    const floatx4 vzero = {0.f, 0.f, 0.f, 0.f};
#pragma unroll
    for (int mt = 0; mt < 4; ++mt)
#pragma unroll
        for (int nt = 0; nt < 4; ++nt) acc[mt][nt] = vzero;

    for (int kc = 0; kc < SD / 32; ++kc) {
        const int k0 = kc * 32;
        gload_lds16(pB + (size_t)kc * T_LEN * RD, &ldsB[(size_t)(w * 16) * 32]);
        short8 afr[4];
#pragma unroll
        for (int mt = 0; mt < 4; ++mt)
            afr[mt] = *reinterpret_cast<const short8*>(ab[mt] + k0);
        __syncthreads();

        short8 bfr[4];
#pragma unroll
        for (int nt = 0; nt < 4; ++nt)
            bfr[nt] = *reinterpret_cast<const short8*>(
                &ldsB[(nt * 16 + l16) * 32 + (quad ^ swz) * 8]);
#pragma unroll
        for (int mt = 0; mt < 4; ++mt)
#pragma unroll
            for (int nt = 0; nt < 4; ++nt)
                acc[mt][nt] = __builtin_amdgcn_mfma_f32_16x16x32_bf16(
                    afr[mt], bfr[nt], acc[mt][nt], 0, 0, 0);
        __syncthreads();
    }

#pragma unroll
    for (int mt = 0; mt < 4; ++mt) {
        const int mb = m0 + mt * 16 + quad * 4;
        const floatx4 bz = *reinterpret_cast<const floatx4*>(bp2 + mb);
#pragma unroll
        for (int nt = 0; nt < 4; ++nt)
#pragma unroll
            for (int j = 0; j < 4; ++j) acc[mt][nt][j] += bz[j];
    }

#pragma unroll
    for (int nt = 0; nt < 4; ++nt) {
        float lm = -1e30f;
#pragma unroll
        for (int mt = 0; mt < 4; ++mt)
#pragma unroll
            for (int j = 0; j < 4; ++j) lm = fmaxf(lm, acc[mt][nt][j]);
        redmax[nt * 256 + l16 * 16 + w * 4 + quad] = lm;
    }
    __syncthreads();

    float lse[4];
#pragma unroll
    for (int nt = 0; nt < 4; ++nt) {
        float gm = -1e30f;
#pragma unroll
        for (int i = 0; i < 16; ++i) gm = fmaxf(gm, redmax[nt * 256 + l16 * 16 + i]);
        float ls = 0.f;
#pragma unroll
        for (int mt = 0; mt < 4; ++mt)
#pragma unroll
            for (int j = 0; j < 4; ++j) ls += __expf(acc[mt][nt][j] - gm);
        redsum[nt * 256 + l16 * 16 + w * 4 + quad] = ls;
        lse[nt] = gm;
    }
    __syncthreads();

#pragma unroll
    for (int nt = 0; nt < 4; ++nt) {
        float tot = 0.f;
#pragma unroll
        for (int i = 0; i < 16; ++i) tot += redsum[nt * 256 + l16 * 16 + i];
        lse[nt] = lse[nt] + __logf(tot);
    }

#pragma unroll
    for (int mt = 0; mt < 4; ++mt) {
        const int mb = m0 + mt * 16 + quad * 4;
#pragma unroll
        for (int nt = 0; nt < 4; ++nt) {
            const int t = n0 + nt * 16 + l16;
#pragma unroll
            for (int j = 0; j < 4; ++j)
                out[(size_t)(mb + j) * T_LEN + t] = acc[mt][nt][j] - lse[nt];
        }
    }
}

extern "C" void kernel_launch(void* const* d_in, const int* in_sizes, int n_in,
                              void* d_out, int out_size, void* d_ws, size_t ws_size,
                              hipStream_t stream)
{
    (void)in_sizes; (void)n_in; (void)out_size; (void)ws_size;
    const float* x     = (const float*)d_in[0];
    const float* Wc    = (const float*)d_in[1];
    const float* bc    = (const float*)d_in[2];
    const float* Wt    = (const float*)d_in[3];
    const float* bt    = (const float*)d_in[4];
    const float* Ws    = (const float*)d_in[5];
    const float* bs    = (const float*)d_in[6];
    const float* Wskip = (const float*)d_in[7];
    const float* bskip = (const float*)d_in[8];
    const float* Wd    = (const float*)d_in[9];
    const float* bd    = (const float*)d_in[10];
    const float* Wp1   = (const float*)d_in[11];
    const float* bp1   = (const float*)d_in[12];
    const float* Wp2   = (const float*)d_in[13];
    const float* bp2   = (const float*)d_in[14];
    float* out = (float*)d_out;

    char* p = (char*)d_ws;
    unsigned short* Gt = (unsigned short*)p;    p += (size_t)T_LEN * KTOT * 2;   // 226.5 MB, [27][T][32]
    unsigned short* ht = (unsigned short*)p;    p += (size_t)T_LEN * SD * 2;     // 134 MB, [16][T][32]
    unsigned short* Wcomb = (unsigned short*)p; p += (size_t)SD * KTOT * 2;
    unsigned short* Wp2b = (unsigned short*)p;  p += (size_t)QD * SD * 2;
    unsigned short* Wg = (unsigned short*)p;    p += (size_t)NL * 64 * 96 * 2;
    unsigned short* Wdb = (unsigned short*)p;   p += (size_t)NL * RD * RD * 2;
    float* hbias = (float*)p;                   p += (size_t)SD * 4;

    // guarded x buffers alias the ht region (dead before gemm1 writes ht):
    // fp32 xaG/xbG: (T+512)*128B = 16.85 MB each; bf16 xabG/xbbG: 8.42 MB each
    char* q = (char*)ht;
    const size_t grows = (size_t)(T_LEN + 2 * GPAD) * RD;
    float* xaG = (float*)q;                     q += grows * 4;
    float* xbG = (float*)q;                     q += grows * 4;
    unsigned short* xabG = (unsigned short*)q;  q += grows * 2;
    unsigned short* xbbG = (unsigned short*)q;  q += grows * 2;
    float* xa = xaG + (size_t)GPAD * RD;
    float* xb = xbG + (size_t)GPAD * RD;
    unsigned short* xab = xabG + (size_t)GPAD * RD;
    unsigned short* xbb = xbbG + (size_t)GPAD * RD;

    k_wcomb<<<(SD * KTOT + 255) / 256, 256, 0, stream>>>(Wp1, Wskip, Wcomb);
    k_hbias<<<1, 512, 0, stream>>>(Wp1, bp1, bskip, hbias);
    k_cvt<<<(QD * SD + 255) / 256, 256, 0, stream>>>(Wp2, Wp2b, QD * SD);
    {
        const int nprep = NL * 64 * 96 + NL * RD * RD;
        k_wprep<<<(nprep + 255) / 256, 256, 0, stream>>>(Wt, Ws, Wd, Wg, Wdb);
    }
    k_conv_init<<<T_LEN / 256, 256, 0, stream>>>(x, Wc, bc, xaG, xabG, xbG, xbbG);

    static const int dil[NL] = {1, 2, 4, 8, 16, 32, 64, 128, 256,
                                1, 2, 4, 8, 16, 32, 64, 128, 256,
                                1, 2, 4, 8, 16, 32, 64, 128, 256};
    const float* cur = xa;
    const unsigned short* curb = xab;
    float* nxt = xb;
    unsigned short* nxtb = xbb;
    for (int i = 0; i < NL; ++i) {
        k_layer_stage<<<T_LEN / 128, 256, 0, stream>>>(
            cur, curb, nxt, nxtb, Gt,
            Wg + (size_t)i * 64 * 96,
            Wdb + (size_t)i * RD * RD,
            bt + (size_t)i * RD,
            bs + (size_t)i * RD,
            bd + (size_t)i * RD,
            dil[i], i);
        { float* tf = (float*)cur; cur = nxt; nxt = tf; }
        { unsigned short* tb = (unsigned short*)curb; curb = nxtb; nxtb = tb; }
    }

    k_gemm1<<<4 * (T_LEN / 128), 256, 0, stream>>>(Wcomb, Gt, hbias, ht);
    k_gemm2_lsm<<<T_LEN / 64, 256, 0, stream>>>(Wp2b, ht, bp2, out);
}

// Round 6
// 973.681 us; speedup vs baseline: 2.6319x; 1.0432x over previous
//
#include <hip/hip_runtime.h>

#define T_LEN 131072
#define RD 32
#define SD 512
#define QD 256
#define NL 27
#define KTOT (NL * RD)   // 864
#define GPAD 256         // guard rows (zeros) on each side of x buffers

// group5 geometry: 5 layers d=1..16, halo 31 -> stage 192 rows per 128 owned
#define G5R 192

typedef __attribute__((ext_vector_type(8))) short short8;
typedef __attribute__((ext_vector_type(4))) float floatx4;

__device__ __forceinline__ unsigned short f2bf(float f) {
    union { float f; unsigned int i; } v; v.f = f;
    unsigned int r = v.i + 0x7fffu + ((v.i >> 16) & 1u);  // RNE
    return (unsigned short)(r >> 16);
}

__device__ __forceinline__ void gload_lds16(const void* g, void* l) {
    __builtin_amdgcn_global_load_lds(
        (const __attribute__((address_space(1))) unsigned int*)g,
        (__attribute__((address_space(3))) unsigned int*)l, 16, 0, 0);
}

// ---------------- initial conv: [1,T] -> [T][32] fp32 + bf16; zero guards ----------------
__global__ __launch_bounds__(256)
void k_conv_init(const float* __restrict__ x, const float* __restrict__ Wc,
                 const float* __restrict__ bc,
                 float* __restrict__ xaG, unsigned short* __restrict__ xabG,
                 float* __restrict__ xbG, unsigned short* __restrict__ xbbG)
{
    const int gid = blockIdx.x * 256 + threadIdx.x;

    if (gid < 4 * GPAD * RD) {
        const int region = gid >> 13;           // GPAD*RD = 8192
        const int idx = gid & (GPAD * RD - 1);
        float* fg; unsigned short* hg;
        const size_t post = (size_t)(GPAD + T_LEN) * RD;
        switch (region) {
            case 0:  fg = xaG;        hg = xabG;        break;
            case 1:  fg = xaG + post; hg = xabG + post; break;
            case 2:  fg = xbG;        hg = xbbG;        break;
            default: fg = xbG + post; hg = xbbG + post; break;
        }
        fg[idx] = 0.f;
        hg[idx] = 0;
    }

    const int t = gid;
    const float xm = (t > 0) ? x[t - 1] : 0.f;
    const float x0 = x[t];
    const float xp = (t < T_LEN - 1) ? x[t + 1] : 0.f;
    float* row = xaG + (size_t)(GPAD + t) * RD;
    unsigned short* rowb = xabG + (size_t)(GPAD + t) * RD;
#pragma unroll
    for (int o = 0; o < RD; ++o) {
        const float v = bc[o] + Wc[o * 3 + 0] * xm + Wc[o * 3 + 1] * x0 + Wc[o * 3 + 2] * xp;
        row[o] = v;
        rowb[o] = f2bf(v);
    }
}

// ---------------- weight prep ----------------
__global__ __launch_bounds__(256)
void k_wprep(const float* __restrict__ Wt, const float* __restrict__ Ws,
             const float* __restrict__ Wd,
             unsigned short* __restrict__ Wg, unsigned short* __restrict__ Wdb)
{
    const int idx = blockIdx.x * 256 + threadIdx.x;
    const int n1 = NL * 64 * 96;
    const int n2 = NL * RD * RD;
    if (idx < n1) {
        const int l = idx / (64 * 96);
        const int rem = idx % (64 * 96);
        const int m = rem / 96;
        const int k = rem % 96;
        const int j = k / 32;
        const int c = k % 32;
        float v;
        if (m < 32) v = Wt[(((size_t)l * RD + m) * RD + c) * 3 + j];
        else        v = Ws[(((size_t)l * RD + (m - 32)) * RD + c) * 3 + j];
        Wg[idx] = f2bf(v);
    } else if (idx < n1 + n2) {
        const int i2 = idx - n1;
        Wdb[i2] = f2bf(Wd[i2]);
    }
}

// ---------------- 5 fused layers d=1..16, halo recompute in LDS ----------------
// 1024 blocks x 384 threads (6 waves x 32 rows = 192 staged rows), 48 KB LDS
// -> 3 blocks/CU (vs R4 group7's 1). Taps come from the bf16 LDS mirror
// (ds_read_b128, no f2bf); residual from fp32 LDS. Tap rows address-clamped
// to [0,191]: clamp only engages for rows whose outputs are provably outside
// the needed window (shrinking-validity argument), so results are exact.
// Barriers are block-local only (2 per layer). Owned rows = e in [32,160)
// = waves 1..4 exactly. Bit-identical numerics to the unfused path.
__global__ __launch_bounds__(384, 4)
void k_group5(const float* __restrict__ xin,          // guarded base + GPAD
              const unsigned short* __restrict__ xinb,
              float* __restrict__ xout,
              unsigned short* __restrict__ xoutb,
              unsigned short* __restrict__ Gt,        // [NL][T][32]
              const unsigned short* __restrict__ WgAll,
              const unsigned short* __restrict__ WdbAll,
              const float* __restrict__ btAll,
              const float* __restrict__ bsAll,
              const float* __restrict__ bdAll,
              int l0)
{
    __shared__ float xs[G5R * RD];                 // 24 KB fp32
    __shared__ unsigned short xsb[G5R * RD];       // 12 KB bf16 mirror
    __shared__ unsigned short gtileL[G5R * RD];    // 12 KB gate

    const int tid = threadIdx.x;
    const int lane = tid & 63;
    const int w = tid >> 6;        // 0..5
    const int quad = lane >> 4;
    const int l16 = lane & 15;
    const int rbase = w * 32;
    const long long t0 = (long long)blockIdx.x * 128;
    const floatx4 vzero = {0.f, 0.f, 0.f, 0.f};
    const bool owned = (w >= 1 && w <= 4);         // rows [32,160)

    // ---- initial fill: this wave's 32 rows, fp32 (4 DMA) + bf16 (2 DMA) ----
    {
        const int r8c = lane >> 3;                     // fp32: 8 rows/KB
        const int scC = (lane & 7) ^ r8c;              // key = row&7
        const int r16c = lane >> 2;                    // bf16: 16 rows/KB
        const int scB = (lane & 3) ^ ((lane >> 3) & 3);// key = (row>>1)&3
        const long long gb = t0 - 32 + rbase;
#pragma unroll
        for (int i = 0; i < 4; ++i)
            gload_lds16(xin + (gb + i * 8 + r8c) * RD + scC * 4,
                        &xs[(rbase + i * 8) * 32]);
#pragma unroll
        for (int i = 0; i < 2; ++i)
            gload_lds16(xinb + (gb + i * 16 + r16c) * RD + scB * 8,
                        &xsb[(rbase + i * 16) * 32]);
    }
    asm volatile("s_waitcnt vmcnt(0)" ::: "memory");
    __syncthreads();

#pragma unroll
    for (int i = 0; i < 5; ++i) {
        const int d = 1 << i;
        const int l = l0 + i;
        const unsigned short* Wg = WgAll + (size_t)l * 64 * 96;
        const unsigned short* Wdb = WdbAll + (size_t)l * RD * RD;
        const float* btp = btAll + (size_t)l * RD;
        const float* bsp = bsAll + (size_t)l * RD;
        const float* bdp = bdAll + (size_t)l * RD;

        short8 afr[3][4];
#pragma unroll
        for (int j = 0; j < 3; ++j)
#pragma unroll
            for (int mt = 0; mt < 4; ++mt)
                afr[j][mt] = *reinterpret_cast<const short8*>(
                    Wg + (size_t)(mt * 16 + l16) * 96 + j * 32 + quad * 8);
        short8 ad[2];
#pragma unroll
        for (int mt = 0; mt < 2; ++mt)
            ad[mt] = *reinterpret_cast<const short8*>(
                Wdb + (size_t)(mt * 16 + l16) * RD + quad * 8);

        // ---- phase A: gated conv, taps from bf16 LDS ----
        floatx4 acc[4][2];
#pragma unroll
        for (int mt = 0; mt < 4; ++mt)
#pragma unroll
            for (int nt = 0; nt < 2; ++nt) acc[mt][nt] = vzero;

#pragma unroll
        for (int nt = 0; nt < 2; ++nt) {
            const int e = rbase + nt * 16 + l16;
#pragma unroll
            for (int j = 0; j < 3; ++j) {
                int et = e + (j - 1) * d;
                et = et < 0 ? 0 : (et > G5R - 1 ? G5R - 1 : et);
                const short8 bb = *reinterpret_cast<const short8*>(
                    &xsb[et * 32 + ((quad ^ ((et >> 1) & 3)) * 8)]);
#pragma unroll
                for (int mt = 0; mt < 4; ++mt)
                    acc[mt][nt] = __builtin_amdgcn_mfma_f32_16x16x32_bf16(
                        afr[j][mt], bb, acc[mt][nt], 0, 0, 0);
            }
        }

        // ---- gate -> gtileL (all rows) + Gt (owned rows) ----
#pragma unroll
        for (int nt = 0; nt < 2; ++nt) {
            const int e = rbase + nt * 16 + l16;
            const int key2 = (e >> 1) & 3;
#pragma unroll
            for (int pair = 0; pair < 2; ++pair) {
                const floatx4 bt4 = *reinterpret_cast<const floatx4*>(btp + pair * 16 + quad * 4);
                const floatx4 bs4 = *reinterpret_cast<const floatx4*>(bsp + pair * 16 + quad * 4);
                ushort4 u;
                unsigned short us[4];
#pragma unroll
                for (int r = 0; r < 4; ++r) {
                    const float a1 = acc[pair][nt][r] + bt4[r];
                    const float a2 = acc[2 + pair][nt][r] + bs4[r];
                    const float th = 1.f - __fdividef(2.f, __expf(2.f * a1) + 1.f);
                    const float sg = __fdividef(1.f, 1.f + __expf(-a2));
                    us[r] = f2bf(th * sg);
                }
                u.x = us[0]; u.y = us[1]; u.z = us[2]; u.w = us[3];
                const int colS = (pair * 2 + (quad >> 1)) ^ key2;
                *reinterpret_cast<ushort4*>(
                    &gtileL[e * 32 + colS * 8 + (quad & 1) * 4]) = u;
                if (owned) {
                    const long long t = t0 + e - 32;
                    *reinterpret_cast<ushort4*>(
                        Gt + ((size_t)l * T_LEN + t) * RD + pair * 16 + quad * 4) = u;
                }
            }
        }

        __syncthreads();   // all phase-A tap reads + gtile stores complete

        // ---- phase B: dense + residual (own rows only -> in-place safe) ----
#pragma unroll
        for (int nt = 0; nt < 2; ++nt) {
            const int e = rbase + nt * 16 + l16;
            const int key2 = (e >> 1) & 3;
            const short8 bg = *reinterpret_cast<const short8*>(
                &gtileL[e * 32 + ((quad ^ key2) * 8)]);
#pragma unroll
            for (int mt = 0; mt < 2; ++mt) {
                const floatx4 a2v = __builtin_amdgcn_mfma_f32_16x16x32_bf16(
                    ad[mt], bg, vzero, 0, 0, 0);
                const int m = mt * 16 + quad * 4;
                const int slotF = (mt * 4 + quad) ^ (e & 7);
                const floatx4 xi = *reinterpret_cast<const floatx4*>(
                    &xs[e * 32 + slotF * 4]);
                const floatx4 bd4 = *reinterpret_cast<const floatx4*>(bdp + m);
                floatx4 o;
                ushort4 ob;
                o[0] = a2v[0] + bd4[0] + xi[0]; ob.x = f2bf(o[0]);
                o[1] = a2v[1] + bd4[1] + xi[1]; ob.y = f2bf(o[1]);
                o[2] = a2v[2] + bd4[2] + xi[2]; ob.z = f2bf(o[2]);
                o[3] = a2v[3] + bd4[3] + xi[3]; ob.w = f2bf(o[3]);
                if (i < 4) {
                    *reinterpret_cast<floatx4*>(&xs[e * 32 + slotF * 4]) = o;
                    const int slotB = (mt * 2 + (quad >> 1)) ^ key2;
                    *reinterpret_cast<ushort4*>(
                        &xsb[e * 32 + slotB * 8 + (quad & 1) * 4]) = ob;
                } else if (owned) {
                    const long long t = t0 + e - 32;
                    *reinterpret_cast<floatx4*>(xout + (size_t)t * RD + m) = o;
                    *reinterpret_cast<ushort4*>(xoutb + (size_t)t * RD + m) = ob;
                }
            }
        }
        __syncthreads();   // new x fully written before next layer's taps
    }
}

// ---------------- single residual layer (d>=32): per-wave async-staged ----------------
__global__ __launch_bounds__(256, 3)
void k_layer_stage(const float* __restrict__ xin,
                   const unsigned short* __restrict__ xinb,
                   float* __restrict__ xout,
                   unsigned short* __restrict__ xoutb,
                   unsigned short* __restrict__ Gt,        // [NL][T][32]
                   const unsigned short* __restrict__ Wg,
                   const unsigned short* __restrict__ Wdb,
                   const float* __restrict__ bt, const float* __restrict__ bs,
                   const float* __restrict__ bd, int d, int layer)
{
    __shared__ unsigned short bandsL[3][128 * 32];  // 24 KB
    __shared__ float centerL[128 * 32];             // 16 KB
    __shared__ unsigned short gtileL[128 * 32];     // 8 KB

    const int tid = threadIdx.x;
    const int lane = tid & 63;
    const int w = tid >> 6;
    const int quad = lane >> 4;
    const int l16 = lane & 15;
    const int rbase = w * 32;
    const bool last = (layer == NL - 1);
    const floatx4 vzero = {0.f, 0.f, 0.f, 0.f};

    const int r16c = lane >> 2;
    const int scB = (lane & 3) ^ ((lane >> 3) & 3);
    const int r8c = lane >> 3;
    const int scC = (lane & 7) ^ r8c;
    const long long gbase = (long long)blockIdx.x * 128 + rbase;

#pragma unroll
    for (int j = 0; j < 3; ++j) {
        const long long b0 = gbase + (long long)(j - 1) * d;
#pragma unroll
        for (int i = 0; i < 2; ++i)
            gload_lds16(xinb + (b0 + i * 16 + r16c) * RD + scB * 8,
                        &bandsL[j][(rbase + i * 16) * 32]);
    }
    if (!last) {
#pragma unroll
        for (int i = 0; i < 4; ++i)
            gload_lds16(xin + (gbase + i * 8 + r8c) * RD + scC * 4,
                        &centerL[(rbase + i * 8) * 32]);
        asm volatile("s_waitcnt vmcnt(4)" ::: "memory");
    } else {
        asm volatile("s_waitcnt vmcnt(0)" ::: "memory");
    }

    short8 afr[3][4];
#pragma unroll
    for (int j = 0; j < 3; ++j)
#pragma unroll
        for (int mt = 0; mt < 4; ++mt)
            afr[j][mt] = *reinterpret_cast<const short8*>(
                Wg + (size_t)(mt * 16 + l16) * 96 + j * 32 + quad * 8);

    floatx4 acc[4][2];
#pragma unroll
    for (int mt = 0; mt < 4; ++mt)
#pragma unroll
        for (int nt = 0; nt < 2; ++nt) acc[mt][nt] = vzero;

#pragma unroll
    for (int nt = 0; nt < 2; ++nt) {
        const int rloc = rbase + nt * 16 + l16;
        const int key2 = (rloc >> 1) & 3;
#pragma unroll
        for (int j = 0; j < 3; ++j) {
            const short8 bb = *reinterpret_cast<const short8*>(
                &bandsL[j][rloc * 32 + ((quad ^ key2) * 8)]);
#pragma unroll
            for (int mt = 0; mt < 4; ++mt)
                acc[mt][nt] = __builtin_amdgcn_mfma_f32_16x16x32_bf16(
                    afr[j][mt], bb, acc[mt][nt], 0, 0, 0);
        }
    }

    if (!last) asm volatile("s_waitcnt vmcnt(0)" ::: "memory");

#pragma unroll
    for (int nt = 0; nt < 2; ++nt) {
        const int rloc = rbase + nt * 16 + l16;
        const int key2 = (rloc >> 1) & 3;
        const long long t = (long long)blockIdx.x * 128 + rloc;
#pragma unroll
        for (int pair = 0; pair < 2; ++pair) {
            const floatx4 bt4 = *reinterpret_cast<const floatx4*>(bt + pair * 16 + quad * 4);
            const floatx4 bs4 = *reinterpret_cast<const floatx4*>(bs + pair * 16 + quad * 4);
            ushort4 u;
            unsigned short us[4];
#pragma unroll
            for (int r = 0; r < 4; ++r) {
                const float a1 = acc[pair][nt][r] + bt4[r];
                const float a2 = acc[2 + pair][nt][r] + bs4[r];
                const float th = 1.f - __fdividef(2.f, __expf(2.f * a1) + 1.f);
                const float sg = __fdividef(1.f, 1.f + __expf(-a2));
                us[r] = f2bf(th * sg);
            }
            u.x = us[0]; u.y = us[1]; u.z = us[2]; u.w = us[3];
            const int cbase = pair * 16 + quad * 4;
            if (!last) {
                const int colS = (pair * 2 + (quad >> 1)) ^ key2;
                *reinterpret_cast<ushort4*>(
                    &gtileL[rloc * 32 + colS * 8 + (quad & 1) * 4]) = u;
            }
            *reinterpret_cast<ushort4*>(
                Gt + ((size_t)layer * T_LEN + t) * RD + cbase) = u;
        }
    }

    if (!last) {
        short8 ad[2];
#pragma unroll
        for (int mt = 0; mt < 2; ++mt)
            ad[mt] = *reinterpret_cast<const short8*>(
                Wdb + (size_t)(mt * 16 + l16) * RD + quad * 8);

#pragma unroll
        for (int nt = 0; nt < 2; ++nt) {
            const int rloc = rbase + nt * 16 + l16;
            const int key2 = (rloc >> 1) & 3;
            const long long t = (long long)blockIdx.x * 128 + rloc;
            const short8 bg = *reinterpret_cast<const short8*>(
                &gtileL[rloc * 32 + ((quad ^ key2) * 8)]);
#pragma unroll
            for (int mt = 0; mt < 2; ++mt) {
                const floatx4 a2v = __builtin_amdgcn_mfma_f32_16x16x32_bf16(
                    ad[mt], bg, vzero, 0, 0, 0);
                const int m = mt * 16 + quad * 4;
                const int c16 = (mt * 4 + quad) ^ (rloc & 7);
                const floatx4 xi = *reinterpret_cast<const floatx4*>(
                    &centerL[rloc * 32 + c16 * 4]);
                const floatx4 bd4 = *reinterpret_cast<const floatx4*>(bd + m);
                floatx4 o;
                ushort4 ob;
                o[0] = a2v[0] + bd4[0] + xi[0]; ob.x = f2bf(o[0]);
                o[1] = a2v[1] + bd4[1] + xi[1]; ob.y = f2bf(o[1]);
                o[2] = a2v[2] + bd4[2] + xi[2]; ob.z = f2bf(o[2]);
                o[3] = a2v[3] + bd4[3] + xi[3]; ob.w = f2bf(o[3]);
                *reinterpret_cast<floatx4*>(xout + (size_t)t * RD + m) = o;
                *reinterpret_cast<ushort4*>(xoutb + (size_t)t * RD + m) = ob;
            }
        }
    }
}

// ---------------- Wcomb (chunk-major [27][512][32]) ----------------
__global__ __launch_bounds__(256)
void k_wcomb(const float* __restrict__ Wp1, const float* __restrict__ Wskip,
             unsigned short* __restrict__ Wcomb)
{
    const int idx = blockIdx.x * 256 + threadIdx.x;
    if (idx >= SD * KTOT) return;
    const int m = idx / KTOT;
    const int k = idx % KTOT;
    const int l = k / RD;
    const int c = k % RD;
    const float* wp1r = Wp1 + (size_t)m * SD;
    const float* wsk = Wskip + (size_t)l * SD * RD + c;
    float acc = 0.f;
    for (int j = 0; j < SD; ++j) acc += wp1r[j] * wsk[(size_t)j * RD];
    Wcomb[((size_t)l * SD + m) * RD + c] = f2bf(acc);
}

// ---------------- hbias ----------------
__global__ __launch_bounds__(512)
void k_hbias(const float* __restrict__ Wp1, const float* __restrict__ bp1,
             const float* __restrict__ bskip, float* __restrict__ hbias)
{
    __shared__ float sb[SD];
    const int tid = threadIdx.x;
    float s = 0.f;
    for (int l = 0; l < NL; ++l) s += bskip[l * SD + tid];
    sb[tid] = s;
    __syncthreads();
    float acc = bp1[tid];
    const float* r = Wp1 + (size_t)tid * SD;
    for (int j = 0; j < SD; ++j) acc += r[j] * sb[j];
    hbias[tid] = acc;
}

// ---------------- fp32 -> bf16 cast ----------------
__global__ __launch_bounds__(256)
void k_cvt(const float* __restrict__ src, unsigned short* __restrict__ dst, int n)
{
    const int i = blockIdx.x * 256 + threadIdx.x;
    if (i < n) dst[i] = f2bf(src[i]);
}

// ---------------- GEMM1, BK=64: two 32-K chunks per barrier pair ----------------
// Halves the vmcnt(0)+barrier drain count: 27 -> 14 (13x64 + 32 tail).
__global__ __launch_bounds__(256)
void k_gemm1(const unsigned short* __restrict__ A,   // Wcomb [27][512][32]
             const unsigned short* __restrict__ B,   // Gt [27][T][32]
             const float* __restrict__ hbias,
             unsigned short* __restrict__ ht)        // [16][T][32]
{
    __shared__ unsigned short ldsA[2][128 * 32];  // 16 KB
    __shared__ unsigned short ldsB[2][128 * 32];  // 16 KB
    const int tid = threadIdx.x;
    const int lane = tid & 63;
    const int w = tid >> 6;
    const int wm = w & 1;
    const int wn = w >> 1;
    const int quad = lane >> 4;
    const int l16 = lane & 15;

    const int g = blockIdx.x;
    const int m0 = ((g >> 3) & 3) * 128;
    const int n0 = ((g & 7) + 8 * (g >> 5)) * 128;

    const int r4 = lane >> 2;
    const int c4 = lane & 3;
    const int srcc = c4 ^ ((r4 >> 1) & 3);
    const int swz = (l16 >> 1) & 3;

    floatx4 acc[4][4];
    const floatx4 vzero = {0.f, 0.f, 0.f, 0.f};
#pragma unroll
    for (int mt = 0; mt < 4; ++mt)
#pragma unroll
        for (int nt = 0; nt < 4; ++nt) acc[mt][nt] = vzero;

    const unsigned short* pA = A + (size_t)(m0 + r4) * RD + srcc * 8;
    const unsigned short* pB = B + (size_t)(n0 + r4) * RD + srcc * 8;

    for (int kc2 = 0; kc2 < 13; ++kc2) {
#pragma unroll
        for (int s = 0; s < 2; ++s) {
            const int kc = kc2 * 2 + s;
#pragma unroll
            for (int c = 0; c < 2; ++c) {
                const int row = w * 32 + c * 16;
                gload_lds16(pA + ((size_t)kc * SD + row) * RD, &ldsA[s][row * 32]);
                gload_lds16(pB + ((size_t)kc * T_LEN + row) * RD, &ldsB[s][row * 32]);
            }
        }
        __syncthreads();

#pragma unroll
        for (int s = 0; s < 2; ++s) {
            short8 afr[4], bfr[4];
#pragma unroll
            for (int mt = 0; mt < 4; ++mt)
                afr[mt] = *reinterpret_cast<const short8*>(
                    &ldsA[s][(wm * 64 + mt * 16 + l16) * 32 + (quad ^ swz) * 8]);
#pragma unroll
            for (int nt = 0; nt < 4; ++nt)
                bfr[nt] = *reinterpret_cast<const short8*>(
                    &ldsB[s][(wn * 64 + nt * 16 + l16) * 32 + (quad ^ swz) * 8]);
#pragma unroll
            for (int mt = 0; mt < 4; ++mt)
#pragma unroll
                for (int nt = 0; nt < 4; ++nt)
                    acc[mt][nt] = __builtin_amdgcn_mfma_f32_16x16x32_bf16(
                        afr[mt], bfr[nt], acc[mt][nt], 0, 0, 0);
        }
        __syncthreads();
    }
    // tail: chunk 26
    {
        const int kc = 26;
#pragma unroll
        for (int c = 0; c < 2; ++c) {
            const int row = w * 32 + c * 16;
            gload_lds16(pA + ((size_t)kc * SD + row) * RD, &ldsA[0][row * 32]);
            gload_lds16(pB + ((size_t)kc * T_LEN + row) * RD, &ldsB[0][row * 32]);
        }
        __syncthreads();
        short8 afr[4], bfr[4];
#pragma unroll
        for (int mt = 0; mt < 4; ++mt)
            afr[mt] = *reinterpret_cast<const short8*>(
                &ldsA[0][(wm * 64 + mt * 16 + l16) * 32 + (quad ^ swz) * 8]);
#pragma unroll
        for (int nt = 0; nt < 4; ++nt)
            bfr[nt] = *reinterpret_cast<const short8*>(
                &ldsB[0][(wn * 64 + nt * 16 + l16) * 32 + (quad ^ swz) * 8]);
#pragma unroll
        for (int mt = 0; mt < 4; ++mt)
#pragma unroll
            for (int nt = 0; nt < 4; ++nt)
                acc[mt][nt] = __builtin_amdgcn_mfma_f32_16x16x32_bf16(
                    afr[mt], bfr[nt], acc[mt][nt], 0, 0, 0);
    }

#pragma unroll
    for (int mt = 0; mt < 4; ++mt) {
        const int m = m0 + wm * 64 + mt * 16 + quad * 4;
        const floatx4 hb = *reinterpret_cast<const floatx4*>(hbias + m);
        const size_t chunkbase = (size_t)(m >> 5) * T_LEN;
        const int mc = m & 31;
#pragma unroll
        for (int nt = 0; nt < 4; ++nt) {
            const int t = n0 + wn * 64 + nt * 16 + l16;
            ushort4 st;
            float v;
            v = acc[mt][nt][0] + hb[0]; st.x = f2bf(v > 0.f ? v : 0.f);
            v = acc[mt][nt][1] + hb[1]; st.y = f2bf(v > 0.f ? v : 0.f);
            v = acc[mt][nt][2] + hb[2]; st.z = f2bf(v > 0.f ? v : 0.f);
            v = acc[mt][nt][3] + hb[3]; st.w = f2bf(v > 0.f ? v : 0.f);
            *reinterpret_cast<ushort4*>(ht + (chunkbase + t) * RD + mc) = st;
        }
    }
}

// ---------------- GEMM2 + fused log_softmax, BK=64 ----------------
__global__ __launch_bounds__(256)
void k_gemm2_lsm(const unsigned short* __restrict__ A,  // Wp2b [256][512] bf16
                 const unsigned short* __restrict__ B,  // ht [16][T][32] bf16
                 const float* __restrict__ bp2,
                 float* __restrict__ out)               // [256][T] fp32
{
    __shared__ unsigned short ldsB[2][64 * 32];  // 8 KB
    __shared__ float redmax[4 * 16 * 16];
    __shared__ float redsum[4 * 16 * 16];
    const int tid = threadIdx.x;
    const int lane = tid & 63;
    const int w = tid >> 6;
    const int quad = lane >> 4;
    const int l16 = lane & 15;
    const int m0 = w * 64;
    const int n0 = blockIdx.x * 64;

    const int r4 = lane >> 2;
    const int c4 = lane & 3;
    const int srcc = c4 ^ ((r4 >> 1) & 3);
    const int swz = (l16 >> 1) & 3;

    const unsigned short* ab[4];
#pragma unroll
    for (int mt = 0; mt < 4; ++mt)
        ab[mt] = A + (size_t)(m0 + mt * 16 + l16) * SD + quad * 8;

    const unsigned short* pB = B + (size_t)(n0 + w * 16 + r4) * RD + srcc * 8;

    floatx4 acc[4][4];
    const floatx4 vzero = {0.f, 0.f, 0.f, 0.f};
#pragma unroll
    for (int mt = 0; mt < 4; ++mt)
#pragma unroll
        for (int nt = 0; nt < 4; ++nt) acc[mt][nt] = vzero;

    for (int kc2 = 0; kc2 < 8; ++kc2) {
        short8 afr[2][4];
#pragma unroll
        for (int s = 0; s < 2; ++s) {
            const int kc = kc2 * 2 + s;
            gload_lds16(pB + (size_t)kc * T_LEN * RD, &ldsB[s][(w * 16) * 32]);
#pragma unroll
            for (int mt = 0; mt < 4; ++mt)
                afr[s][mt] = *reinterpret_cast<const short8*>(ab[mt] + kc * 32);
        }
        __syncthreads();

#pragma unroll
        for (int s = 0; s < 2; ++s) {
            short8 bfr[4];
#pragma unroll
            for (int nt = 0; nt < 4; ++nt)
                bfr[nt] = *reinterpret_cast<const short8*>(
                    &ldsB[s][(nt * 16 + l16) * 32 + (quad ^ swz) * 8]);
#pragma unroll
            for (int mt = 0; mt < 4; ++mt)
#pragma unroll
                for (int nt = 0; nt < 4; ++nt)
                    acc[mt][nt] = __builtin_amdgcn_mfma_f32_16x16x32_bf16(
                        afr[s][mt], bfr[nt], acc[mt][nt], 0, 0, 0);
        }
        __syncthreads();
    }

#pragma unroll
    for (int mt = 0; mt < 4; ++mt) {
        const int mb = m0 + mt * 16 + quad * 4;
        const floatx4 bz = *reinterpret_cast<const floatx4*>(bp2 + mb);
#pragma unroll
        for (int nt = 0; nt < 4; ++nt)
#pragma unroll
            for (int j = 0; j < 4; ++j) acc[mt][nt][j] += bz[j];
    }

#pragma unroll
    for (int nt = 0; nt < 4; ++nt) {
        float lm = -1e30f;
#pragma unroll
        for (int mt = 0; mt < 4; ++mt)
#pragma unroll
            for (int j = 0; j < 4; ++j) lm = fmaxf(lm, acc[mt][nt][j]);
        redmax[nt * 256 + l16 * 16 + w * 4 + quad] = lm;
    }
    __syncthreads();

    float lse[4];
#pragma unroll
    for (int nt = 0; nt < 4; ++nt) {
        float gm = -1e30f;
#pragma unroll
        for (int i = 0; i < 16; ++i) gm = fmaxf(gm, redmax[nt * 256 + l16 * 16 + i]);
        float ls = 0.f;
#pragma unroll
        for (int mt = 0; mt < 4; ++mt)
#pragma unroll
            for (int j = 0; j < 4; ++j) ls += __expf(acc[mt][nt][j] - gm);
        redsum[nt * 256 + l16 * 16 + w * 4 + quad] = ls;
        lse[nt] = gm;
    }
    __syncthreads();

#pragma unroll
    for (int nt = 0; nt < 4; ++nt) {
        float tot = 0.f;
#pragma unroll
        for (int i = 0; i < 16; ++i) tot += redsum[nt * 256 + l16 * 16 + i];
        lse[nt] = lse[nt] + __logf(tot);
    }

#pragma unroll
    for (int mt = 0; mt < 4; ++mt) {
        const int mb = m0 + mt * 16 + quad * 4;
#pragma unroll
        for (int nt = 0; nt < 4; ++nt) {
            const int t = n0 + nt * 16 + l16;
#pragma unroll
            for (int j = 0; j < 4; ++j)
                out[(size_t)(mb + j) * T_LEN + t] = acc[mt][nt][j] - lse[nt];
        }
    }
}

extern "C" void kernel_launch(void* const* d_in, const int* in_sizes, int n_in,
                              void* d_out, int out_size, void* d_ws, size_t ws_size,
                              hipStream_t stream)
{
    (void)in_sizes; (void)n_in; (void)out_size; (void)ws_size;
    const float* x     = (const float*)d_in[0];
    const float* Wc    = (const float*)d_in[1];
    const float* bc    = (const float*)d_in[2];
    const float* Wt    = (const float*)d_in[3];
    const float* bt    = (const float*)d_in[4];
    const float* Ws    = (const float*)d_in[5];
    const float* bs    = (const float*)d_in[6];
    const float* Wskip = (const float*)d_in[7];
    const float* bskip = (const float*)d_in[8];
    const float* Wd    = (const float*)d_in[9];
    const float* bd    = (const float*)d_in[10];
    const float* Wp1   = (const float*)d_in[11];
    const float* bp1   = (const float*)d_in[12];
    const float* Wp2   = (const float*)d_in[13];
    const float* bp2   = (const float*)d_in[14];
    float* out = (float*)d_out;

    char* p = (char*)d_ws;
    unsigned short* Gt = (unsigned short*)p;    p += (size_t)T_LEN * KTOT * 2;   // 226.5 MB
    unsigned short* ht = (unsigned short*)p;    p += (size_t)T_LEN * SD * 2;     // 134 MB
    unsigned short* Wcomb = (unsigned short*)p; p += (size_t)SD * KTOT * 2;
    unsigned short* Wp2b = (unsigned short*)p;  p += (size_t)QD * SD * 2;
    unsigned short* Wg = (unsigned short*)p;    p += (size_t)NL * 64 * 96 * 2;
    unsigned short* Wdb = (unsigned short*)p;   p += (size_t)NL * RD * RD * 2;
    float* hbias = (float*)p;                   p += (size_t)SD * 4;

    // guarded x buffers alias the ht region (dead before gemm1 writes ht)
    char* q = (char*)ht;
    const size_t grows = (size_t)(T_LEN + 2 * GPAD) * RD;
    float* xaG = (float*)q;                     q += grows * 4;
    float* xbG = (float*)q;                     q += grows * 4;
    unsigned short* xabG = (unsigned short*)q;  q += grows * 2;
    unsigned short* xbbG = (unsigned short*)q;  q += grows * 2;
    float* xa = xaG + (size_t)GPAD * RD;
    float* xb = xbG + (size_t)GPAD * RD;
    unsigned short* xab = xabG + (size_t)GPAD * RD;
    unsigned short* xbb = xbbG + (size_t)GPAD * RD;

    k_wcomb<<<(SD * KTOT + 255) / 256, 256, 0, stream>>>(Wp1, Wskip, Wcomb);
    k_hbias<<<1, 512, 0, stream>>>(Wp1, bp1, bskip, hbias);
    k_cvt<<<(QD * SD + 255) / 256, 256, 0, stream>>>(Wp2, Wp2b, QD * SD);
    {
        const int nprep = NL * 64 * 96 + NL * RD * RD;
        k_wprep<<<(nprep + 255) / 256, 256, 0, stream>>>(Wt, Ws, Wd, Wg, Wdb);
    }
    k_conv_init<<<T_LEN / 256, 256, 0, stream>>>(x, Wc, bc, xaG, xabG, xbG, xbbG);

    const float* cur = xa;
    const unsigned short* curb = xab;
    float* nxt = xb;
    unsigned short* nxtb = xbb;
    static const int dsing[4] = {32, 64, 128, 256};
    for (int s = 0; s < 3; ++s) {
        // layers 9s .. 9s+4 (d=1..16) fused
        k_group5<<<T_LEN / 128, 384, 0, stream>>>(
            cur, curb, nxt, nxtb, Gt, Wg, Wdb, bt, bs, bd, 9 * s);
        { float* tf = (float*)cur; cur = nxt; nxt = tf; }
        { unsigned short* tb = (unsigned short*)curb; curb = nxtb; nxtb = tb; }
        // layers 9s+5 .. 9s+8 (d=32..256) single
        for (int j = 0; j < 4; ++j) {
            const int li = 9 * s + 5 + j;
            k_layer_stage<<<T_LEN / 128, 256, 0, stream>>>(
                cur, curb, nxt, nxtb, Gt,
                Wg + (size_t)li * 64 * 96,
                Wdb + (size_t)li * RD * RD,
                bt + (size_t)li * RD,
                bs + (size_t)li * RD,
                bd + (size_t)li * RD,
                dsing[j], li);
            { float* tf = (float*)cur; cur = nxt; nxt = tf; }
            { unsigned short* tb = (unsigned short*)curb; curb = nxtb; nxtb = tb; }
        }
    }

    k_gemm1<<<4 * (T_LEN / 128), 256, 0, stream>>>(Wcomb, Gt, hbias, ht);
    k_gemm2_lsm<<<T_LEN / 64, 256, 0, stream>>>(Wp2b, ht, bp2, out);
}